// Round 2
// baseline (1725.174 us; speedup 1.0000x reference)
//
#include <hip/hip_runtime.h>
#include <cstdint>
#include <cstddef>

typedef __bf16 bf16_t;
typedef __attribute__((ext_vector_type(8))) __bf16 bf16x8;
typedef __attribute__((ext_vector_type(4))) float f32x4;

constexpr int D  = 1024;   // d_model
constexpr int TT = 1024;   // seq len
constexpr int BB = 4;      // batch
constexpr int NH = 16;     // heads
constexpr int HS = 64;     // head size
constexpr int MR = BB * TT; // 4096 rows
constexpr int HF = 4096;   // ffn hidden

// split 8 consecutive f32 into hi/lo bf16 pairs (emulated-fp32 operand)
__device__ inline void split_f32x8(const float* __restrict__ p, bf16x8& hi, bf16x8& lo)
{
    float4 v0 = *(const float4*)p;
    float4 v1 = *(const float4*)(p + 4);
    float vals[8] = {v0.x, v0.y, v0.z, v0.w, v1.x, v1.y, v1.z, v1.w};
#pragma unroll
    for (int j = 0; j < 8; ++j) {
        bf16_t h = (bf16_t)vals[j];
        hi[j] = h;
        lo[j] = (bf16_t)(vals[j] - (float)h);
    }
}

// ---------------------------------------------------------------------------
// RMSNorm: f32 in -> f32 out. One block (256 thr) per row of 1024.
// ---------------------------------------------------------------------------
__global__ __launch_bounds__(256) void rmsnorm_kernel(const float* __restrict__ x,
                                                      const float* __restrict__ gamma,
                                                      float* __restrict__ out)
{
    int row = blockIdx.x;
    int t   = threadIdx.x;
    const float* xr = x + (size_t)row * D;
    float4 xv = *(const float4*)(xr + t * 4);
    float ss = xv.x * xv.x + xv.y * xv.y + xv.z * xv.z + xv.w * xv.w;
#pragma unroll
    for (int m = 1; m < 64; m <<= 1) ss += __shfl_xor(ss, m, 64);
    __shared__ float part[4];
    if ((t & 63) == 0) part[t >> 6] = ss;
    __syncthreads();
    float tot   = part[0] + part[1] + part[2] + part[3];
    float scale = rsqrtf(tot * (1.0f / D) + 1e-6f);
    float4 gv = *(const float4*)(gamma + t * 4);
    float4 o;
    o.x = xv.x * scale * gv.x;
    o.y = xv.y * scale * gv.y;
    o.z = xv.z * scale * gv.z;
    o.w = xv.w * scale * gv.w;
    *(float4*)(out + (size_t)row * D + t * 4) = o;
}

// ---------------------------------------------------------------------------
// Split-precision GEMM: out[M,N] = act(A_f32[M,K] @ W_f32[K,N] + bias)(+resid)
// Both operands split hi/lo bf16; 3 MFMAs per tile (hh + hl + lh) ~ fp32 acc.
// 64x64 tile, 4 waves (32x32 quadrants), BK=32, mfma 16x16x32 bf16.
// ---------------------------------------------------------------------------
template<bool RELU, bool RESID>
__global__ __launch_bounds__(256) void gemm_kernel(const float* __restrict__ A,
                                                   const float* __restrict__ W,
                                                   const float* __restrict__ bias,
                                                   const float* __restrict__ resid,
                                                   float* __restrict__ out,
                                                   int N, int K)
{
    __shared__ bf16_t Ah[64][40];   // [m][k] hi, +8 pad
    __shared__ bf16_t Al[64][40];   // [m][k] lo
    __shared__ bf16_t Wh[64][40];   // [n][k] hi (transposed)
    __shared__ bf16_t Wl[64][40];   // [n][k] lo

    int t  = threadIdx.x;
    int m0 = blockIdx.y * 64, n0 = blockIdx.x * 64;
    int l  = t & 63, wid = t >> 6;
    int wr = (wid >> 1) * 32, wc = (wid & 1) * 32;
    int lr = l & 15, lg = l >> 4;

    f32x4 acc[2][2] = {};

    int arow = t >> 2,  acol = (t & 3) * 8;   // A staging: 64 rows x 32 k
    int wk   = t >> 3,  wn   = (t & 7) * 8;   // W staging: 32 k x 64 n

    for (int kk = 0; kk < K; kk += 32) {
        __syncthreads();
        // stage A tile split hi/lo
        bf16x8 ah, al;
        split_f32x8(A + (size_t)(m0 + arow) * K + kk + acol, ah, al);
        *(bf16x8*)&Ah[arow][acol] = ah;
        *(bf16x8*)&Al[arow][acol] = al;
        // stage W tile split hi/lo, transposed
        const float* wp = W + (size_t)(kk + wk) * N + n0 + wn;
        float4 w0 = *(const float4*)wp;
        float4 w1 = *(const float4*)(wp + 4);
        float wv[8] = {w0.x, w0.y, w0.z, w0.w, w1.x, w1.y, w1.z, w1.w};
#pragma unroll
        for (int j = 0; j < 8; ++j) {
            bf16_t h = (bf16_t)wv[j];
            Wh[wn + j][wk] = h;
            Wl[wn + j][wk] = (bf16_t)(wv[j] - (float)h);
        }
        __syncthreads();

        bf16x8 afh[2], afl[2], bfh[2], bfl[2];
#pragma unroll
        for (int m = 0; m < 2; ++m) {
            afh[m] = *(const bf16x8*)&Ah[wr + m * 16 + lr][lg * 8];
            afl[m] = *(const bf16x8*)&Al[wr + m * 16 + lr][lg * 8];
        }
#pragma unroll
        for (int n = 0; n < 2; ++n) {
            bfh[n] = *(const bf16x8*)&Wh[wc + n * 16 + lr][lg * 8];
            bfl[n] = *(const bf16x8*)&Wl[wc + n * 16 + lr][lg * 8];
        }
#pragma unroll
        for (int m = 0; m < 2; ++m)
#pragma unroll
            for (int n = 0; n < 2; ++n) {
                acc[m][n] = __builtin_amdgcn_mfma_f32_16x16x32_bf16(afh[m], bfh[n], acc[m][n], 0, 0, 0);
                acc[m][n] = __builtin_amdgcn_mfma_f32_16x16x32_bf16(afh[m], bfl[n], acc[m][n], 0, 0, 0);
                acc[m][n] = __builtin_amdgcn_mfma_f32_16x16x32_bf16(afl[m], bfh[n], acc[m][n], 0, 0, 0);
            }
    }

#pragma unroll
    for (int m = 0; m < 2; ++m) {
#pragma unroll
        for (int n = 0; n < 2; ++n) {
            int col = n0 + wc + n * 16 + lr;
            float bval = bias[col];
#pragma unroll
            for (int r = 0; r < 4; ++r) {
                int row = m0 + wr + m * 16 + lg * 4 + r;
                float v = acc[m][n][r] + bval;
                if (RELU)  v = (v >= 0.0f) ? v : 0.1f * v;
                if (RESID) v += resid[(size_t)row * N + col];
                out[(size_t)row * N + col] = v;
            }
        }
    }
}

// ---------------------------------------------------------------------------
// Flash attention, split-precision. Block = 256 thr (4 waves), one block per
// (b, h, 64 q-rows). Each wave owns 16 q rows. scores = (Q K^T) * 8.
// Q/K/V/P all hi/lo split; 3 MFMAs per product. Q/K f32 from global,
// V transposed via LDS, P via padded LDS.
// ---------------------------------------------------------------------------
template<bool CAUSAL>
__global__ __launch_bounds__(256) void attn_kernel(const float* __restrict__ q,
                                                   const float* __restrict__ k,
                                                   const float* __restrict__ v,
                                                   float* __restrict__ out)
{
    __shared__ bf16_t Vth[64][72];     // [e][kk] hi, +8 pad
    __shared__ bf16_t Vtl[64][72];     // [e][kk] lo
    __shared__ bf16_t Ph[4][16][72];   // per-wave [qrow][kk] hi
    __shared__ bf16_t Pl[4][16][72];   // per-wave [qrow][kk] lo

    int tid = threadIdx.x;
    int qt = blockIdx.x, h = blockIdx.y, b = blockIdx.z;
    int l = tid & 63, w = tid >> 6;
    int lr = l & 15, lg = l >> 4;
    int qbase = qt * 64;

    const float* qp = q + ((size_t)(b * TT + qbase + w * 16 + lr)) * D + h * HS;
    bf16x8 aqh[2], aql[2];
    split_f32x8(qp + lg * 8,      aqh[0], aql[0]);
    split_f32x8(qp + 32 + lg * 8, aqh[1], aql[1]);

    float mrow[4], lsum[4];
    f32x4 acc_o[4] = {};
#pragma unroll
    for (int r = 0; r < 4; ++r) { mrow[r] = -1e30f; lsum[r] = 0.0f; }

    int ktmax = CAUSAL ? qt : (TT / 64 - 1);
    for (int kt = 0; kt <= ktmax; ++kt) {
        int kbase = kt * 64;
        __syncthreads();
        // stage V tile transposed + split: Vt[e][kk]
#pragma unroll
        for (int rr = 0; rr < 2; ++rr) {
            int vrow = (tid >> 3) + rr * 32;
            int vcol = (tid & 7) * 8;
            const float* vp = v + ((size_t)(b * TT + kbase + vrow)) * D + h * HS + vcol;
            float4 v0 = *(const float4*)vp;
            float4 v1 = *(const float4*)(vp + 4);
            float vv[8] = {v0.x, v0.y, v0.z, v0.w, v1.x, v1.y, v1.z, v1.w};
#pragma unroll
            for (int j = 0; j < 8; ++j) {
                bf16_t hh = (bf16_t)vv[j];
                Vth[vcol + j][vrow] = hh;
                Vtl[vcol + j][vrow] = (bf16_t)(vv[j] - (float)hh);
            }
        }
        __syncthreads();

        // S = Q K^T  (16 q-rows x 64 k-cols per wave), split 3-MFMA
        f32x4 accs[4];
        const float* kp = k + ((size_t)(b * TT + kbase + lr)) * D + h * HS;
#pragma unroll
        for (int nt = 0; nt < 4; ++nt) {
            const float* kpn = kp + (size_t)nt * 16 * D;
            bf16x8 bkh0, bkl0, bkh1, bkl1;
            split_f32x8(kpn + lg * 8,      bkh0, bkl0);
            split_f32x8(kpn + 32 + lg * 8, bkh1, bkl1);
            f32x4 s = {};
            s = __builtin_amdgcn_mfma_f32_16x16x32_bf16(aqh[0], bkh0, s, 0, 0, 0);
            s = __builtin_amdgcn_mfma_f32_16x16x32_bf16(aqh[0], bkl0, s, 0, 0, 0);
            s = __builtin_amdgcn_mfma_f32_16x16x32_bf16(aql[0], bkh0, s, 0, 0, 0);
            s = __builtin_amdgcn_mfma_f32_16x16x32_bf16(aqh[1], bkh1, s, 0, 0, 0);
            s = __builtin_amdgcn_mfma_f32_16x16x32_bf16(aqh[1], bkl1, s, 0, 0, 0);
            s = __builtin_amdgcn_mfma_f32_16x16x32_bf16(aql[1], bkh1, s, 0, 0, 0);
            accs[nt] = s * 8.0f;   // * sqrt(head_size), faithful to reference
        }

        if (CAUSAL && kt == qt) {
#pragma unroll
            for (int nt = 0; nt < 4; ++nt)
#pragma unroll
                for (int r = 0; r < 4; ++r) {
                    int qrow = qbase + w * 16 + lg * 4 + r;
                    int kcol = kbase + nt * 16 + lr;
                    if (kcol > qrow) accs[nt][r] = -1e30f;
                }
        }

        // online softmax (row-wise over the 16 lanes holding this row)
        float alpha[4];
#pragma unroll
        for (int r = 0; r < 4; ++r) {
            float mx = fmaxf(fmaxf(accs[0][r], accs[1][r]), fmaxf(accs[2][r], accs[3][r]));
#pragma unroll
            for (int msk = 1; msk < 16; msk <<= 1) mx = fmaxf(mx, __shfl_xor(mx, msk, 64));
            float mnew = fmaxf(mrow[r], mx);
            float sum = 0.0f;
#pragma unroll
            for (int nt = 0; nt < 4; ++nt) {
                float p = __expf(accs[nt][r] - mnew);
                accs[nt][r] = p;
                sum += p;
            }
#pragma unroll
            for (int msk = 1; msk < 16; msk <<= 1) sum += __shfl_xor(sum, msk, 64);
            alpha[r] = __expf(mrow[r] - mnew);
            lsum[r]  = lsum[r] * alpha[r] + sum;
            mrow[r]  = mnew;
        }
#pragma unroll
        for (int et = 0; et < 4; ++et)
#pragma unroll
            for (int r = 0; r < 4; ++r) acc_o[et][r] *= alpha[r];

        // P -> LDS split hi/lo (C/D layout -> A-operand re-layout)
#pragma unroll
        for (int nt = 0; nt < 4; ++nt)
#pragma unroll
            for (int r = 0; r < 4; ++r) {
                float p = accs[nt][r];
                bf16_t hh = (bf16_t)p;
                Ph[w][lg * 4 + r][nt * 16 + lr] = hh;
                Pl[w][lg * 4 + r][nt * 16 + lr] = (bf16_t)(p - (float)hh);
            }
        __syncthreads();

        // O += P @ V  (split 3-MFMA per k-half)
        bf16x8 aph0 = *(const bf16x8*)&Ph[w][lr][lg * 8];
        bf16x8 apl0 = *(const bf16x8*)&Pl[w][lr][lg * 8];
        bf16x8 aph1 = *(const bf16x8*)&Ph[w][lr][32 + lg * 8];
        bf16x8 apl1 = *(const bf16x8*)&Pl[w][lr][32 + lg * 8];
#pragma unroll
        for (int et = 0; et < 4; ++et) {
            bf16x8 bvh0 = *(const bf16x8*)&Vth[et * 16 + lr][lg * 8];
            bf16x8 bvl0 = *(const bf16x8*)&Vtl[et * 16 + lr][lg * 8];
            bf16x8 bvh1 = *(const bf16x8*)&Vth[et * 16 + lr][32 + lg * 8];
            bf16x8 bvl1 = *(const bf16x8*)&Vtl[et * 16 + lr][32 + lg * 8];
            acc_o[et] = __builtin_amdgcn_mfma_f32_16x16x32_bf16(aph0, bvh0, acc_o[et], 0, 0, 0);
            acc_o[et] = __builtin_amdgcn_mfma_f32_16x16x32_bf16(aph0, bvl0, acc_o[et], 0, 0, 0);
            acc_o[et] = __builtin_amdgcn_mfma_f32_16x16x32_bf16(apl0, bvh0, acc_o[et], 0, 0, 0);
            acc_o[et] = __builtin_amdgcn_mfma_f32_16x16x32_bf16(aph1, bvh1, acc_o[et], 0, 0, 0);
            acc_o[et] = __builtin_amdgcn_mfma_f32_16x16x32_bf16(aph1, bvl1, acc_o[et], 0, 0, 0);
            acc_o[et] = __builtin_amdgcn_mfma_f32_16x16x32_bf16(apl1, bvh1, acc_o[et], 0, 0, 0);
        }
    }

    float* op = out + ((size_t)(b * TT + qbase + w * 16)) * D + h * HS;
#pragma unroll
    for (int r = 0; r < 4; ++r) {
        float inv = 1.0f / lsum[r];
#pragma unroll
        for (int et = 0; et < 4; ++et)
            op[(size_t)(lg * 4 + r) * D + et * 16 + lr] = acc_o[et][r] * inv;
    }
}

// ---------------------------------------------------------------------------
extern "C" void kernel_launch(void* const* d_in, const int* in_sizes, int n_in,
                              void* d_out, int out_size, void* d_ws, size_t ws_size,
                              hipStream_t stream)
{
    const float* x     = (const float*)d_in[0];
    const float* Wq    = (const float*)d_in[1];
    const float* bq    = (const float*)d_in[2];
    const float* Wk    = (const float*)d_in[3];
    const float* bk    = (const float*)d_in[4];
    const float* Wv    = (const float*)d_in[5];
    const float* bv    = (const float*)d_in[6];
    const float* Wp    = (const float*)d_in[7];
    const float* bp    = (const float*)d_in[8];
    const float* gamma = (const float*)d_in[9];
    const float* W1    = (const float*)d_in[10];
    const float* b1    = (const float*)d_in[11];
    const float* W2    = (const float*)d_in[12];
    const float* b2    = (const float*)d_in[13];
    float* out = (float*)d_out;

    // f32 workspace, 6 x 16MB slots (h1 spans the 4 dead q/k/v/ao slots)
    float* nrm  = (float*)d_ws;
    float* buf0 = nrm  + (size_t)MR * D;
    float* buf1 = buf0 + (size_t)MR * D;
    float* buf2 = buf1 + (size_t)MR * D;
    float* buf3 = buf2 + (size_t)MR * D;
    float* bbuf = buf3 + (size_t)MR * D;
    float* h1   = buf0;            // 64MB spanning buf0..buf3
    float* abuf = out;             // d_out as scratch for 'a'; dead before final write

    dim3 blk(256);
    dim3 gN(D / 64, MR / 64);     // N=1024 GEMMs
    dim3 gF(HF / 64, MR / 64);    // N=4096 GEMM
    dim3 gA(TT / 64, NH, BB);     // attention

    // a = x + attn(rmsnorm(x), causal=false)
    rmsnorm_kernel<<<MR, blk, 0, stream>>>(x, gamma, nrm);
    gemm_kernel<false, false><<<gN, blk, 0, stream>>>(nrm, Wq, bq, nullptr, buf0, D, D);
    gemm_kernel<false, false><<<gN, blk, 0, stream>>>(nrm, Wk, bk, nullptr, buf1, D, D);
    gemm_kernel<false, false><<<gN, blk, 0, stream>>>(nrm, Wv, bv, nullptr, buf2, D, D);
    attn_kernel<false><<<gA, blk, 0, stream>>>(buf0, buf1, buf2, buf3);
    gemm_kernel<false, true><<<gN, blk, 0, stream>>>(buf3, Wp, bp, x, abuf, D, D);

    // b = x + ffwd(rmsnorm(a))
    rmsnorm_kernel<<<MR, blk, 0, stream>>>(abuf, gamma, nrm);
    gemm_kernel<true, false><<<gF, blk, 0, stream>>>(nrm, W1, b1, nullptr, h1, HF, D);
    gemm_kernel<false, true><<<gN, blk, 0, stream>>>(h1, W2, b2, x, bbuf, D, HF);

    // c = b + attn(rmsnorm(b), causal=true)
    rmsnorm_kernel<<<MR, blk, 0, stream>>>(bbuf, gamma, nrm);
    gemm_kernel<false, false><<<gN, blk, 0, stream>>>(nrm, Wq, bq, nullptr, buf0, D, D);
    gemm_kernel<false, false><<<gN, blk, 0, stream>>>(nrm, Wk, bk, nullptr, buf1, D, D);
    gemm_kernel<false, false><<<gN, blk, 0, stream>>>(nrm, Wv, bv, nullptr, buf2, D, D);
    attn_kernel<true><<<gA, blk, 0, stream>>>(buf0, buf1, buf2, buf3);
    gemm_kernel<false, true><<<gN, blk, 0, stream>>>(buf3, Wp, bp, bbuf, out, D, D);
}

// Round 3
// 1018.966 us; speedup vs baseline: 1.6931x; 1.6931x over previous
//
#include <hip/hip_runtime.h>
#include <cstdint>
#include <cstddef>

typedef __bf16 bf16_t;
typedef __attribute__((ext_vector_type(8))) __bf16 bf16x8;
typedef __attribute__((ext_vector_type(4))) __bf16 bf16x4;
typedef __attribute__((ext_vector_type(4))) float f32x4;

constexpr int D  = 1024;   // d_model
constexpr int TT = 1024;   // seq len
constexpr int BB = 4;      // batch
constexpr int NH = 16;     // heads
constexpr int HS = 64;     // head size
constexpr int MR = BB * TT; // 4096 rows
constexpr int HF = 4096;   // ffn hidden

__device__ inline void gload_lds16(const bf16_t* g, bf16_t* l)
{
    __builtin_amdgcn_global_load_lds(
        (const __attribute__((address_space(1))) void*)g,
        (__attribute__((address_space(3))) void*)l, 16, 0, 0);
}

// ---------------------------------------------------------------------------
// RMSNorm: f32 in -> bf16 hi/lo planes out. One block (256 thr) per row.
// ---------------------------------------------------------------------------
__global__ __launch_bounds__(256) void rmsnorm_kernel(const float* __restrict__ x,
                                                      const float* __restrict__ gamma,
                                                      bf16_t* __restrict__ oh,
                                                      bf16_t* __restrict__ ol)
{
    int row = blockIdx.x;
    int t   = threadIdx.x;
    const float* xr = x + (size_t)row * D;
    float4 xv = *(const float4*)(xr + t * 4);
    float ss = xv.x * xv.x + xv.y * xv.y + xv.z * xv.z + xv.w * xv.w;
#pragma unroll
    for (int m = 1; m < 64; m <<= 1) ss += __shfl_xor(ss, m, 64);
    __shared__ float part[4];
    if ((t & 63) == 0) part[t >> 6] = ss;
    __syncthreads();
    float tot   = part[0] + part[1] + part[2] + part[3];
    float scale = rsqrtf(tot * (1.0f / D) + 1e-6f);
    float4 gv = *(const float4*)(gamma + t * 4);
    float vals[4] = {xv.x * scale * gv.x, xv.y * scale * gv.y,
                     xv.z * scale * gv.z, xv.w * scale * gv.w};
    bf16x4 vh, vl;
#pragma unroll
    for (int j = 0; j < 4; ++j) {
        bf16_t h = (bf16_t)vals[j];
        vh[j] = h;
        vl[j] = (bf16_t)(vals[j] - (float)h);
    }
    *(bf16x4*)(oh + (size_t)row * D + t * 4) = vh;
    *(bf16x4*)(ol + (size_t)row * D + t * 4) = vl;
}

// ---------------------------------------------------------------------------
// Weight convert: W f32 [K][N] -> wt hi plane [N][K] bf16, lo plane at +N*K.
// 64x64 tile via padded LDS transpose. Grid (K/64, N/64), 256 thr.
// ---------------------------------------------------------------------------
__global__ __launch_bounds__(256) void convw_kernel(const float* __restrict__ W,
                                                    bf16_t* __restrict__ wt,
                                                    int K, int N)
{
    __shared__ float sld[64][65];
    int t = threadIdx.x;
    int k0 = blockIdx.x * 64, n0 = blockIdx.y * 64;
    int kr = t >> 4, nc = (t & 15) * 4;
#pragma unroll
    for (int p = 0; p < 4; ++p) {
        int k = p * 16 + kr;
        float4 v = *(const float4*)(W + (size_t)(k0 + k) * N + n0 + nc);
        sld[k][nc] = v.x; sld[k][nc + 1] = v.y; sld[k][nc + 2] = v.z; sld[k][nc + 3] = v.w;
    }
    __syncthreads();
    int n = t >> 2, kh = (t & 3) * 16;
    bf16x8 h0, l0, h1, l1;
#pragma unroll
    for (int j = 0; j < 8; ++j) {
        float v = sld[kh + j][n];
        bf16_t h = (bf16_t)v;
        h0[j] = h; l0[j] = (bf16_t)(v - (float)h);
    }
#pragma unroll
    for (int j = 0; j < 8; ++j) {
        float v = sld[kh + 8 + j][n];
        bf16_t h = (bf16_t)v;
        h1[j] = h; l1[j] = (bf16_t)(v - (float)h);
    }
    size_t o = (size_t)(n0 + n) * K + k0 + kh;
    size_t plane = (size_t)N * K;
    *(bf16x8*)(wt + o)             = h0;
    *(bf16x8*)(wt + o + 8)         = h1;
    *(bf16x8*)(wt + plane + o)     = l0;
    *(bf16x8*)(wt + plane + o + 8) = l1;
}

// ---------------------------------------------------------------------------
// Split-precision GEMM, 128x128 tile, BK=32, 4 waves (64x64 each, 4x4 frags).
// A hi/lo bf16 [M][K]; W hi/lo bf16 [N][K] (pre-transposed). 3 MFMAs per pair.
// global_load_lds(16B) staging into linear LDS, XOR-swizzled source+read.
// OUTM: 0 = f32 out, 1 = bf16 hi/lo planes out.
// ---------------------------------------------------------------------------
template<int OUTM, bool RELU, bool RESID>
__global__ __launch_bounds__(256, 2) void gemm_kernel(
    const bf16_t* __restrict__ Ahp, const bf16_t* __restrict__ Alp,
    const bf16_t* __restrict__ Whp, const bf16_t* __restrict__ Wlp,
    const float* __restrict__ bias, const float* resid,
    float* outf, bf16_t* __restrict__ outh, bf16_t* __restrict__ outl,
    int N, int K)
{
    __shared__ bf16_t sA[2][128][32];   // [hi/lo][m][k], linear (gload_lds dest)
    __shared__ bf16_t sW[2][128][32];   // [hi/lo][n][k]

    int t = threadIdx.x;
    int l = t & 63, w = t >> 6;
    int lr = l & 15, lg = l >> 4;

    // XCD-aware block swizzle (all grids have nwg % 8 == 0)
    int gx  = gridDim.x;
    int nwg = gx * gridDim.y;
    int bid = blockIdx.y * gx + blockIdx.x;
    int s   = (bid & 7) * (nwg >> 3) + (bid >> 3);
    int nb  = s % gx, mb = s / gx;
    int m0 = mb * 128, n0 = nb * 128;
    int wr = (w >> 1) * 64, wc = (w & 1) * 64;

    f32x4 acc[4][4] = {};

    // staging: wave w covers rows [w*32, w*32+32) of each plane, 2 chunks x16 rows
    int srow = (l >> 2);      // 0..15 within chunk
    int sch  = l & 3;         // 16B slot within 64B row

    for (int kk = 0; kk < K; kk += 32) {
        __syncthreads();
#pragma unroll
        for (int c = 0; c < 2; ++c) {
            int rbase = w * 32 + c * 16;
            int row = rbase + srow;
            int f = (row >> 1) & 3;
            size_t goff = (size_t)row * K + kk + (size_t)((sch ^ f)) * 8;
            gload_lds16(Ahp + (size_t)m0 * K + goff, &sA[0][rbase][0]);
            gload_lds16(Alp + (size_t)m0 * K + goff, &sA[1][rbase][0]);
            gload_lds16(Whp + (size_t)n0 * K + goff, &sW[0][rbase][0]);
            gload_lds16(Wlp + (size_t)n0 * K + goff, &sW[1][rbase][0]);
        }
        __syncthreads();

        bf16x8 a0[4], a1[4], b0[4], b1[4];
#pragma unroll
        for (int m = 0; m < 4; ++m) {
            int row = wr + m * 16 + lr;
            int sl = lg ^ ((row >> 1) & 3);
            a0[m] = *(const bf16x8*)&sA[0][row][sl * 8];
            a1[m] = *(const bf16x8*)&sA[1][row][sl * 8];
        }
#pragma unroll
        for (int n = 0; n < 4; ++n) {
            int row = wc + n * 16 + lr;
            int sl = lg ^ ((row >> 1) & 3);
            b0[n] = *(const bf16x8*)&sW[0][row][sl * 8];
            b1[n] = *(const bf16x8*)&sW[1][row][sl * 8];
        }
        // hh pass, then hl, then lh: dependent ops on same acc are 16 apart
#pragma unroll
        for (int m = 0; m < 4; ++m)
#pragma unroll
            for (int n = 0; n < 4; ++n)
                acc[m][n] = __builtin_amdgcn_mfma_f32_16x16x32_bf16(a0[m], b0[n], acc[m][n], 0, 0, 0);
#pragma unroll
        for (int m = 0; m < 4; ++m)
#pragma unroll
            for (int n = 0; n < 4; ++n)
                acc[m][n] = __builtin_amdgcn_mfma_f32_16x16x32_bf16(a0[m], b1[n], acc[m][n], 0, 0, 0);
#pragma unroll
        for (int m = 0; m < 4; ++m)
#pragma unroll
            for (int n = 0; n < 4; ++n)
                acc[m][n] = __builtin_amdgcn_mfma_f32_16x16x32_bf16(a1[m], b0[n], acc[m][n], 0, 0, 0);
    }

#pragma unroll
    for (int m = 0; m < 4; ++m) {
#pragma unroll
        for (int n = 0; n < 4; ++n) {
            int col = n0 + wc + n * 16 + lr;
            float bv = bias[col];
#pragma unroll
            for (int r = 0; r < 4; ++r) {
                int row = m0 + wr + m * 16 + lg * 4 + r;
                float v = acc[m][n][r] + bv;
                if (RELU)  v = (v >= 0.0f) ? v : 0.1f * v;
                if (RESID) v += resid[(size_t)row * N + col];
                if (OUTM == 0) {
                    outf[(size_t)row * N + col] = v;
                } else {
                    bf16_t h = (bf16_t)v;
                    outh[(size_t)row * N + col] = h;
                    outl[(size_t)row * N + col] = (bf16_t)(v - (float)h);
                }
            }
        }
    }
}

// ---------------------------------------------------------------------------
// Flash attention, split-precision, hi/lo plane inputs/outputs.
// Block = 256 thr (4 waves), one block per (b, h, 64 q-rows).
// ---------------------------------------------------------------------------
template<bool CAUSAL>
__global__ __launch_bounds__(256) void attn_kernel(
    const bf16_t* __restrict__ qhp, const bf16_t* __restrict__ qlp,
    const bf16_t* __restrict__ khp, const bf16_t* __restrict__ klp,
    const bf16_t* __restrict__ vhp, const bf16_t* __restrict__ vlp,
    bf16_t* __restrict__ oh, bf16_t* __restrict__ ol)
{
    __shared__ bf16_t Vth[64][72];     // [e][kk] hi, +8 pad
    __shared__ bf16_t Vtl[64][72];     // [e][kk] lo
    __shared__ bf16_t Ph[4][16][72];   // per-wave [qrow][kk] hi
    __shared__ bf16_t Pl[4][16][72];   // per-wave [qrow][kk] lo

    int tid = threadIdx.x;
    int qt = blockIdx.x, h = blockIdx.y, b = blockIdx.z;
    int l = tid & 63, w = tid >> 6;
    int lr = l & 15, lg = l >> 4;
    int qbase = qt * 64;

    size_t qoff = ((size_t)(b * TT + qbase + w * 16 + lr)) * D + h * HS;
    bf16x8 aqh[2], aql[2];
    aqh[0] = *(const bf16x8*)(qhp + qoff + lg * 8);
    aql[0] = *(const bf16x8*)(qlp + qoff + lg * 8);
    aqh[1] = *(const bf16x8*)(qhp + qoff + 32 + lg * 8);
    aql[1] = *(const bf16x8*)(qlp + qoff + 32 + lg * 8);

    float mrow[4], lsum[4];
    f32x4 acc_o[4] = {};
#pragma unroll
    for (int r = 0; r < 4; ++r) { mrow[r] = -1e30f; lsum[r] = 0.0f; }

    int ktmax = CAUSAL ? qt : (TT / 64 - 1);
    for (int kt = 0; kt <= ktmax; ++kt) {
        int kbase = kt * 64;
        __syncthreads();
        // stage V tile transposed (hi/lo copy, no cvt)
#pragma unroll
        for (int rr = 0; rr < 2; ++rr) {
            int vrow = (tid >> 3) + rr * 32;
            int vcol = (tid & 7) * 8;
            size_t voff = ((size_t)(b * TT + kbase + vrow)) * D + h * HS + vcol;
            bf16x8 vvh = *(const bf16x8*)(vhp + voff);
            bf16x8 vvl = *(const bf16x8*)(vlp + voff);
#pragma unroll
            for (int j = 0; j < 8; ++j) {
                Vth[vcol + j][vrow] = vvh[j];
                Vtl[vcol + j][vrow] = vvl[j];
            }
        }
        __syncthreads();

        // S = Q K^T  (16 q-rows x 64 k-cols per wave), split 3-MFMA
        f32x4 accs[4];
        size_t koff = ((size_t)(b * TT + kbase + lr)) * D + h * HS;
#pragma unroll
        for (int nt = 0; nt < 4; ++nt) {
            size_t ko = koff + (size_t)nt * 16 * D;
            bf16x8 bkh0 = *(const bf16x8*)(khp + ko + lg * 8);
            bf16x8 bkl0 = *(const bf16x8*)(klp + ko + lg * 8);
            bf16x8 bkh1 = *(const bf16x8*)(khp + ko + 32 + lg * 8);
            bf16x8 bkl1 = *(const bf16x8*)(klp + ko + 32 + lg * 8);
            f32x4 s = {};
            s = __builtin_amdgcn_mfma_f32_16x16x32_bf16(aqh[0], bkh0, s, 0, 0, 0);
            s = __builtin_amdgcn_mfma_f32_16x16x32_bf16(aqh[0], bkl0, s, 0, 0, 0);
            s = __builtin_amdgcn_mfma_f32_16x16x32_bf16(aql[0], bkh0, s, 0, 0, 0);
            s = __builtin_amdgcn_mfma_f32_16x16x32_bf16(aqh[1], bkh1, s, 0, 0, 0);
            s = __builtin_amdgcn_mfma_f32_16x16x32_bf16(aqh[1], bkl1, s, 0, 0, 0);
            s = __builtin_amdgcn_mfma_f32_16x16x32_bf16(aql[1], bkh1, s, 0, 0, 0);
            accs[nt] = s * 8.0f;   // * sqrt(head_size), faithful to reference
        }

        if (CAUSAL && kt == qt) {
#pragma unroll
            for (int nt = 0; nt < 4; ++nt)
#pragma unroll
                for (int r = 0; r < 4; ++r) {
                    int qrow = qbase + w * 16 + lg * 4 + r;
                    int kcol = kbase + nt * 16 + lr;
                    if (kcol > qrow) accs[nt][r] = -1e30f;
                }
        }

        // online softmax
        float alpha[4];
#pragma unroll
        for (int r = 0; r < 4; ++r) {
            float mx = fmaxf(fmaxf(accs[0][r], accs[1][r]), fmaxf(accs[2][r], accs[3][r]));
#pragma unroll
            for (int msk = 1; msk < 16; msk <<= 1) mx = fmaxf(mx, __shfl_xor(mx, msk, 64));
            float mnew = fmaxf(mrow[r], mx);
            float sum = 0.0f;
#pragma unroll
            for (int nt = 0; nt < 4; ++nt) {
                float p = __expf(accs[nt][r] - mnew);
                accs[nt][r] = p;
                sum += p;
            }
#pragma unroll
            for (int msk = 1; msk < 16; msk <<= 1) sum += __shfl_xor(sum, msk, 64);
            alpha[r] = __expf(mrow[r] - mnew);
            lsum[r]  = lsum[r] * alpha[r] + sum;
            mrow[r]  = mnew;
        }
#pragma unroll
        for (int et = 0; et < 4; ++et)
#pragma unroll
            for (int r = 0; r < 4; ++r) acc_o[et][r] *= alpha[r];

        // P -> LDS split hi/lo (C/D layout -> A-operand re-layout)
#pragma unroll
        for (int nt = 0; nt < 4; ++nt)
#pragma unroll
            for (int r = 0; r < 4; ++r) {
                float p = accs[nt][r];
                bf16_t hh = (bf16_t)p;
                Ph[w][lg * 4 + r][nt * 16 + lr] = hh;
                Pl[w][lg * 4 + r][nt * 16 + lr] = (bf16_t)(p - (float)hh);
            }
        __syncthreads();

        // O += P @ V  (split 3-MFMA per k-half)
        bf16x8 aph0 = *(const bf16x8*)&Ph[w][lr][lg * 8];
        bf16x8 apl0 = *(const bf16x8*)&Pl[w][lr][lg * 8];
        bf16x8 aph1 = *(const bf16x8*)&Ph[w][lr][32 + lg * 8];
        bf16x8 apl1 = *(const bf16x8*)&Pl[w][lr][32 + lg * 8];
#pragma unroll
        for (int et = 0; et < 4; ++et) {
            bf16x8 bvh0 = *(const bf16x8*)&Vth[et * 16 + lr][lg * 8];
            bf16x8 bvl0 = *(const bf16x8*)&Vtl[et * 16 + lr][lg * 8];
            bf16x8 bvh1 = *(const bf16x8*)&Vth[et * 16 + lr][32 + lg * 8];
            bf16x8 bvl1 = *(const bf16x8*)&Vtl[et * 16 + lr][32 + lg * 8];
            acc_o[et] = __builtin_amdgcn_mfma_f32_16x16x32_bf16(aph0, bvh0, acc_o[et], 0, 0, 0);
            acc_o[et] = __builtin_amdgcn_mfma_f32_16x16x32_bf16(aph0, bvl0, acc_o[et], 0, 0, 0);
            acc_o[et] = __builtin_amdgcn_mfma_f32_16x16x32_bf16(apl0, bvh0, acc_o[et], 0, 0, 0);
            acc_o[et] = __builtin_amdgcn_mfma_f32_16x16x32_bf16(aph1, bvh1, acc_o[et], 0, 0, 0);
            acc_o[et] = __builtin_amdgcn_mfma_f32_16x16x32_bf16(aph1, bvl1, acc_o[et], 0, 0, 0);
            acc_o[et] = __builtin_amdgcn_mfma_f32_16x16x32_bf16(apl1, bvh1, acc_o[et], 0, 0, 0);
        }
    }

    size_t obase = ((size_t)(b * TT + qbase + w * 16)) * D + h * HS;
#pragma unroll
    for (int r = 0; r < 4; ++r) {
        float inv = 1.0f / lsum[r];
#pragma unroll
        for (int et = 0; et < 4; ++et) {
            float v = acc_o[et][r] * inv;
            bf16_t hh = (bf16_t)v;
            size_t idx = obase + (size_t)(lg * 4 + r) * D + et * 16 + lr;
            oh[idx] = hh;
            ol[idx] = (bf16_t)(v - (float)hh);
        }
    }
}

// ---------------------------------------------------------------------------
extern "C" void kernel_launch(void* const* d_in, const int* in_sizes, int n_in,
                              void* d_out, int out_size, void* d_ws, size_t ws_size,
                              hipStream_t stream)
{
    const float* x     = (const float*)d_in[0];
    const float* Wq    = (const float*)d_in[1];
    const float* bq    = (const float*)d_in[2];
    const float* Wk    = (const float*)d_in[3];
    const float* bk    = (const float*)d_in[4];
    const float* Wv    = (const float*)d_in[5];
    const float* bv    = (const float*)d_in[6];
    const float* Wp    = (const float*)d_in[7];
    const float* bp    = (const float*)d_in[8];
    const float* gamma = (const float*)d_in[9];
    const float* W1    = (const float*)d_in[10];
    const float* b1    = (const float*)d_in[11];
    const float* W2    = (const float*)d_in[12];
    const float* b2    = (const float*)d_in[13];
    float* out = (float*)d_out;

    // workspace layout, 96 MB total:
    // [nrm hi 8][nrm lo 8][q hi 8][q lo 8][k hi 8][k lo 8][v hi 8][v lo 8][extra 16][wslot 16]
    char* base = (char*)d_ws;
    bf16_t* nrmH = (bf16_t*)(base);
    bf16_t* nrmL = (bf16_t*)(base + (8u  << 20));
    bf16_t* qH   = (bf16_t*)(base + (16u << 20));
    bf16_t* qL   = (bf16_t*)(base + (24u << 20));
    bf16_t* kH   = (bf16_t*)(base + (32u << 20));
    bf16_t* kL   = (bf16_t*)(base + (40u << 20));
    bf16_t* vH   = (bf16_t*)(base + (48u << 20));
    bf16_t* vL   = (bf16_t*)(base + (56u << 20));
    bf16_t* h1H  = qH;                               // 32 MB spans qH..kL
    bf16_t* h1L  = vH;                               // 32 MB spans vH, vL, extra
    bf16_t* wsl  = (bf16_t*)(base + (80u << 20));    // 16 MB weight slot
    // ao planes alias nrm planes (nrm dead once QKV gemms finish)
    bf16_t* aoH = nrmH, *aoL = nrmL;
    float* abuf = out;   // 'a' lives in d_out, dead before final write
    float* bbuf = out;   // 'b' overwrites 'a' in d_out, dead-safe (a unused after)

    // weight slot sub-offsets for the attention phase (hi+lo = 2*D*D elems each)
    bf16_t* wq = wsl;
    bf16_t* wk = wsl + (size_t)2 * D * D;
    bf16_t* wv = wsl + (size_t)4 * D * D;
    bf16_t* wp = wsl + (size_t)6 * D * D;

    dim3 blk(256);
    dim3 gcvD(D / 64, D / 64);
    dim3 gcv1(D / 64, HF / 64);
    dim3 gcv2(HF / 64, D / 64);
    dim3 gN(D / 128, MR / 128);
    dim3 gF(HF / 128, MR / 128);
    dim3 gA(TT / 64, NH, BB);

    // ---- a = x + attn(rmsnorm(x), causal=false)
    rmsnorm_kernel<<<MR, blk, 0, stream>>>(x, gamma, nrmH, nrmL);
    convw_kernel<<<gcvD, blk, 0, stream>>>(Wq, wq, D, D);
    convw_kernel<<<gcvD, blk, 0, stream>>>(Wk, wk, D, D);
    convw_kernel<<<gcvD, blk, 0, stream>>>(Wv, wv, D, D);
    convw_kernel<<<gcvD, blk, 0, stream>>>(Wp, wp, D, D);
    gemm_kernel<1, false, false><<<gN, blk, 0, stream>>>(nrmH, nrmL, wq, wq + (size_t)D * D, bq, nullptr, nullptr, qH, qL, D, D);
    gemm_kernel<1, false, false><<<gN, blk, 0, stream>>>(nrmH, nrmL, wk, wk + (size_t)D * D, bk, nullptr, nullptr, kH, kL, D, D);
    gemm_kernel<1, false, false><<<gN, blk, 0, stream>>>(nrmH, nrmL, wv, wv + (size_t)D * D, bv, nullptr, nullptr, vH, vL, D, D);
    attn_kernel<false><<<gA, blk, 0, stream>>>(qH, qL, kH, kL, vH, vL, aoH, aoL);
    gemm_kernel<0, false, true><<<gN, blk, 0, stream>>>(aoH, aoL, wp, wp + (size_t)D * D, bp, x, abuf, nullptr, nullptr, D, D);

    // ---- b = x + ffwd(rmsnorm(a))
    rmsnorm_kernel<<<MR, blk, 0, stream>>>(abuf, gamma, nrmH, nrmL);
    convw_kernel<<<gcv1, blk, 0, stream>>>(W1, wsl, D, HF);
    gemm_kernel<1, true, false><<<gF, blk, 0, stream>>>(nrmH, nrmL, wsl, wsl + (size_t)HF * D, b1, nullptr, nullptr, h1H, h1L, HF, D);
    convw_kernel<<<gcv2, blk, 0, stream>>>(W2, wsl, HF, D);
    gemm_kernel<0, false, true><<<gN, blk, 0, stream>>>(h1H, h1L, wsl, wsl + (size_t)D * HF, b2, x, bbuf, nullptr, nullptr, D, HF);

    // ---- c = b + attn(rmsnorm(b), causal=true)
    rmsnorm_kernel<<<MR, blk, 0, stream>>>(bbuf, gamma, nrmH, nrmL);
    convw_kernel<<<gcvD, blk, 0, stream>>>(Wq, wq, D, D);
    convw_kernel<<<gcvD, blk, 0, stream>>>(Wk, wk, D, D);
    convw_kernel<<<gcvD, blk, 0, stream>>>(Wv, wv, D, D);
    convw_kernel<<<gcvD, blk, 0, stream>>>(Wp, wp, D, D);
    gemm_kernel<1, false, false><<<gN, blk, 0, stream>>>(nrmH, nrmL, wq, wq + (size_t)D * D, bq, nullptr, nullptr, qH, qL, D, D);
    gemm_kernel<1, false, false><<<gN, blk, 0, stream>>>(nrmH, nrmL, wk, wk + (size_t)D * D, bk, nullptr, nullptr, kH, kL, D, D);
    gemm_kernel<1, false, false><<<gN, blk, 0, stream>>>(nrmH, nrmL, wv, wv + (size_t)D * D, bv, nullptr, nullptr, vH, vL, D, D);
    attn_kernel<true><<<gA, blk, 0, stream>>>(qH, qL, kH, kL, vH, vL, aoH, aoL);
    gemm_kernel<0, false, true><<<gN, blk, 0, stream>>>(aoH, aoL, wp, wp + (size_t)D * D, bp, bbuf, out, nullptr, nullptr, D, D);
}

// Round 4
// 787.068 us; speedup vs baseline: 2.1919x; 1.2946x over previous
//
#include <hip/hip_runtime.h>
#include <cstdint>
#include <cstddef>

typedef __bf16 bf16_t;
typedef __attribute__((ext_vector_type(8))) __bf16 bf16x8;
typedef __attribute__((ext_vector_type(4))) __bf16 bf16x4;
typedef __attribute__((ext_vector_type(4))) float f32x4;

constexpr int D  = 1024;   // d_model
constexpr int TT = 1024;   // seq len
constexpr int BB = 4;      // batch
constexpr int NH = 16;     // heads
constexpr int HS = 64;     // head size
constexpr int MR = BB * TT; // 4096 rows
constexpr int HF = 4096;   // ffn hidden

__device__ inline void gload_lds16(const bf16_t* g, bf16_t* l)
{
    __builtin_amdgcn_global_load_lds(
        (const __attribute__((address_space(1))) void*)g,
        (__attribute__((address_space(3))) void*)l, 16, 0, 0);
}

// ---------------------------------------------------------------------------
// RMSNorm: f32 in -> bf16 hi/lo planes out. One block (256 thr) per row.
// ---------------------------------------------------------------------------
__global__ __launch_bounds__(256) void rmsnorm_kernel(const float* __restrict__ x,
                                                      const float* __restrict__ gamma,
                                                      bf16_t* __restrict__ oh,
                                                      bf16_t* __restrict__ ol)
{
    int row = blockIdx.x;
    int t   = threadIdx.x;
    const float* xr = x + (size_t)row * D;
    float4 xv = *(const float4*)(xr + t * 4);
    float ss = xv.x * xv.x + xv.y * xv.y + xv.z * xv.z + xv.w * xv.w;
#pragma unroll
    for (int m = 1; m < 64; m <<= 1) ss += __shfl_xor(ss, m, 64);
    __shared__ float part[4];
    if ((t & 63) == 0) part[t >> 6] = ss;
    __syncthreads();
    float tot   = part[0] + part[1] + part[2] + part[3];
    float scale = rsqrtf(tot * (1.0f / D) + 1e-6f);
    float4 gv = *(const float4*)(gamma + t * 4);
    float vals[4] = {xv.x * scale * gv.x, xv.y * scale * gv.y,
                     xv.z * scale * gv.z, xv.w * scale * gv.w};
    bf16x4 vh, vl;
#pragma unroll
    for (int j = 0; j < 4; ++j) {
        bf16_t h = (bf16_t)vals[j];
        vh[j] = h;
        vl[j] = (bf16_t)(vals[j] - (float)h);
    }
    *(bf16x4*)(oh + (size_t)row * D + t * 4) = vh;
    *(bf16x4*)(ol + (size_t)row * D + t * 4) = vl;
}

// ---------------------------------------------------------------------------
// concat 3x [1024] f32 biases into one [3072] buffer
// ---------------------------------------------------------------------------
__global__ __launch_bounds__(256) void concat_bias_kernel(const float* __restrict__ a,
                                                          const float* __restrict__ b,
                                                          const float* __restrict__ c,
                                                          float* __restrict__ o)
{
    int i = blockIdx.x * 256 + threadIdx.x;
    o[i] = i < 1024 ? a[i] : (i < 2048 ? b[i - 1024] : c[i - 2048]);
}

// ---------------------------------------------------------------------------
// Weight convert: W f32 [K][N] -> dH/dL bf16 [N][K] planes (transposed).
// 64x64 tile via padded LDS transpose. Grid (K/64, N/64), 256 thr.
// ---------------------------------------------------------------------------
__global__ __launch_bounds__(256) void convw_kernel(const float* __restrict__ W,
                                                    bf16_t* __restrict__ dH,
                                                    bf16_t* __restrict__ dL,
                                                    int K, int N)
{
    __shared__ float sld[64][65];
    int t = threadIdx.x;
    int k0 = blockIdx.x * 64, n0 = blockIdx.y * 64;
    int kr = t >> 4, nc = (t & 15) * 4;
#pragma unroll
    for (int p = 0; p < 4; ++p) {
        int k = p * 16 + kr;
        float4 v = *(const float4*)(W + (size_t)(k0 + k) * N + n0 + nc);
        sld[k][nc] = v.x; sld[k][nc + 1] = v.y; sld[k][nc + 2] = v.z; sld[k][nc + 3] = v.w;
    }
    __syncthreads();
    int n = t >> 2, kh = (t & 3) * 16;
    bf16x8 h0, l0, h1, l1;
#pragma unroll
    for (int j = 0; j < 8; ++j) {
        float v = sld[kh + j][n];
        bf16_t h = (bf16_t)v;
        h0[j] = h; l0[j] = (bf16_t)(v - (float)h);
    }
#pragma unroll
    for (int j = 0; j < 8; ++j) {
        float v = sld[kh + 8 + j][n];
        bf16_t h = (bf16_t)v;
        h1[j] = h; l1[j] = (bf16_t)(v - (float)h);
    }
    size_t o = (size_t)(n0 + n) * K + k0 + kh;
    *(bf16x8*)(dH + o)     = h0;
    *(bf16x8*)(dH + o + 8) = h1;
    *(bf16x8*)(dL + o)     = l0;
    *(bf16x8*)(dL + o + 8) = l1;
}

// ---------------------------------------------------------------------------
// Split-precision GEMM, 128x128 tile, BK=32, 4 waves (64x64 each, 4x4 frags).
// A hi/lo bf16 [M][K]; W hi/lo bf16 [N][K] (pre-transposed). 3 MFMAs per pair.
// global_load_lds(16B) staging into linear LDS, XOR-swizzled source+read.
// OUTM: 0 = f32 out, 1 = bf16 hi/lo planes out.
// ---------------------------------------------------------------------------
template<int OUTM, bool RELU, bool RESID>
__global__ __launch_bounds__(256, 2) void gemm_kernel(
    const bf16_t* __restrict__ Ahp, const bf16_t* __restrict__ Alp,
    const bf16_t* __restrict__ Whp, const bf16_t* __restrict__ Wlp,
    const float* __restrict__ bias, const float* resid,
    float* outf, bf16_t* __restrict__ outh, bf16_t* __restrict__ outl,
    int N, int K)
{
    __shared__ bf16_t sA[2][128][32];   // [hi/lo][m][k], linear (gload_lds dest)
    __shared__ bf16_t sW[2][128][32];   // [hi/lo][n][k]

    int t = threadIdx.x;
    int l = t & 63, w = t >> 6;
    int lr = l & 15, lg = l >> 4;

    // XCD-aware block swizzle (all grids have nwg % 8 == 0)
    int gx  = gridDim.x;
    int nwg = gx * gridDim.y;
    int bid = blockIdx.y * gx + blockIdx.x;
    int s   = (bid & 7) * (nwg >> 3) + (bid >> 3);
    int nb  = s % gx, mb = s / gx;
    int m0 = mb * 128, n0 = nb * 128;
    int wr = (w >> 1) * 64, wc = (w & 1) * 64;

    f32x4 acc[4][4] = {};

    // staging: wave w covers rows [w*32, w*32+32) of each plane, 2 chunks x16 rows
    int srow = (l >> 2);      // 0..15 within chunk
    int sch  = l & 3;         // 16B slot within 64B row

    for (int kk = 0; kk < K; kk += 32) {
        __syncthreads();
#pragma unroll
        for (int c = 0; c < 2; ++c) {
            int rbase = w * 32 + c * 16;
            int row = rbase + srow;
            int f = (row >> 1) & 3;
            size_t goff = (size_t)row * K + kk + (size_t)((sch ^ f)) * 8;
            gload_lds16(Ahp + (size_t)m0 * K + goff, &sA[0][rbase][0]);
            gload_lds16(Alp + (size_t)m0 * K + goff, &sA[1][rbase][0]);
            gload_lds16(Whp + (size_t)n0 * K + goff, &sW[0][rbase][0]);
            gload_lds16(Wlp + (size_t)n0 * K + goff, &sW[1][rbase][0]);
        }
        __syncthreads();

        bf16x8 a0[4], a1[4], b0[4], b1[4];
#pragma unroll
        for (int m = 0; m < 4; ++m) {
            int row = wr + m * 16 + lr;
            int sl = lg ^ ((row >> 1) & 3);
            a0[m] = *(const bf16x8*)&sA[0][row][sl * 8];
            a1[m] = *(const bf16x8*)&sA[1][row][sl * 8];
        }
#pragma unroll
        for (int n = 0; n < 4; ++n) {
            int row = wc + n * 16 + lr;
            int sl = lg ^ ((row >> 1) & 3);
            b0[n] = *(const bf16x8*)&sW[0][row][sl * 8];
            b1[n] = *(const bf16x8*)&sW[1][row][sl * 8];
        }
        // hh pass, then hl, then lh: dependent ops on same acc are 16 apart
#pragma unroll
        for (int m = 0; m < 4; ++m)
#pragma unroll
            for (int n = 0; n < 4; ++n)
                acc[m][n] = __builtin_amdgcn_mfma_f32_16x16x32_bf16(a0[m], b0[n], acc[m][n], 0, 0, 0);
#pragma unroll
        for (int m = 0; m < 4; ++m)
#pragma unroll
            for (int n = 0; n < 4; ++n)
                acc[m][n] = __builtin_amdgcn_mfma_f32_16x16x32_bf16(a0[m], b1[n], acc[m][n], 0, 0, 0);
#pragma unroll
        for (int m = 0; m < 4; ++m)
#pragma unroll
            for (int n = 0; n < 4; ++n)
                acc[m][n] = __builtin_amdgcn_mfma_f32_16x16x32_bf16(a1[m], b0[n], acc[m][n], 0, 0, 0);
    }

#pragma unroll
    for (int m = 0; m < 4; ++m) {
#pragma unroll
        for (int n = 0; n < 4; ++n) {
            int col = n0 + wc + n * 16 + lr;
            float bv = bias[col];
#pragma unroll
            for (int r = 0; r < 4; ++r) {
                int row = m0 + wr + m * 16 + lg * 4 + r;
                float v = acc[m][n][r] + bv;
                if (RELU)  v = (v >= 0.0f) ? v : 0.1f * v;
                if (RESID) v += resid[(size_t)row * N + col];
                if (OUTM == 0) {
                    outf[(size_t)row * N + col] = v;
                } else {
                    bf16_t h = (bf16_t)v;
                    outh[(size_t)row * N + col] = h;
                    outl[(size_t)row * N + col] = (bf16_t)(v - (float)h);
                }
            }
        }
    }
}

// ---------------------------------------------------------------------------
// Flash attention from fused QKV planes (row stride 3D; q/k/v at col 0/D/2D).
// Block = 256 thr (4 waves), 128 q-rows per block (32/wave).
// QK^T split-precision (3 MFMA/pair); PV pure bf16-hi (P in [0,1], V post-
// softmax: bf16 rounding ~2e-3 abs, negligible). V staged hi-only, pad 70.
// ---------------------------------------------------------------------------
template<bool CAUSAL>
__global__ __launch_bounds__(256, 2) void attn_kernel(
    const bf16_t* __restrict__ qkvH, const bf16_t* __restrict__ qkvL,
    bf16_t* __restrict__ oh, bf16_t* __restrict__ ol)
{
    __shared__ bf16_t Vth[64][70];     // [e][kk] hi, pad 70 (~2-way banks)
    __shared__ bf16_t Ph[4][32][70];   // per-wave [qrow][kk] hi

    int tid = threadIdx.x;
    int qb = blockIdx.x, h = blockIdx.y, b = blockIdx.z;
    int l = tid & 63, w = tid >> 6;
    int lr = l & 15, lg = l >> 4;
    int qbase = qb * 128;
    const int QS = 3 * D;

    // Q frags: 32 rows per wave (2 x 16-row frags), hi/lo, both k-halves
    bf16x8 aqh[2][2], aql[2][2];
#pragma unroll
    for (int m = 0; m < 2; ++m) {
        size_t qoff = (size_t)(b * TT + qbase + w * 32 + m * 16 + lr) * QS + h * HS;
#pragma unroll
        for (int c = 0; c < 2; ++c) {
            aqh[m][c] = *(const bf16x8*)(qkvH + qoff + c * 32 + lg * 8);
            aql[m][c] = *(const bf16x8*)(qkvL + qoff + c * 32 + lg * 8);
        }
    }

    float mrow[2][4], lsum[2][4];
    f32x4 acc_o[2][4] = {};
#pragma unroll
    for (int m = 0; m < 2; ++m)
#pragma unroll
        for (int r = 0; r < 4; ++r) { mrow[m][r] = -1e30f; lsum[m][r] = 0.0f; }

    int ktmax = CAUSAL ? (2 * qb + 1) : (TT / 64 - 1);
    for (int kt = 0; kt <= ktmax; ++kt) {
        int kbase = kt * 64;
        __syncthreads();
        // stage V tile (hi only) transposed: Vth[e][kk]
#pragma unroll
        for (int rr = 0; rr < 2; ++rr) {
            int vrow = (tid >> 3) + rr * 32;
            int vcol = (tid & 7) * 8;
            size_t voff = (size_t)(b * TT + kbase + vrow) * QS + 2 * D + h * HS + vcol;
            bf16x8 vv = *(const bf16x8*)(qkvH + voff);
#pragma unroll
            for (int j = 0; j < 8; ++j) Vth[vcol + j][vrow] = vv[j];
        }
        __syncthreads();

        // S = Q K^T  (32 q-rows x 64 k-cols per wave), split 3-MFMA
        f32x4 accs[2][4];
        size_t koff = (size_t)(b * TT + kbase + lr) * QS + D + h * HS;
#pragma unroll
        for (int nt = 0; nt < 4; ++nt) {
            size_t ko = koff + (size_t)(nt * 16) * QS;
            bf16x8 bkh0 = *(const bf16x8*)(qkvH + ko + lg * 8);
            bf16x8 bkl0 = *(const bf16x8*)(qkvL + ko + lg * 8);
            bf16x8 bkh1 = *(const bf16x8*)(qkvH + ko + 32 + lg * 8);
            bf16x8 bkl1 = *(const bf16x8*)(qkvL + ko + 32 + lg * 8);
#pragma unroll
            for (int m = 0; m < 2; ++m) {
                f32x4 s = {};
                s = __builtin_amdgcn_mfma_f32_16x16x32_bf16(aqh[m][0], bkh0, s, 0, 0, 0);
                s = __builtin_amdgcn_mfma_f32_16x16x32_bf16(aqh[m][0], bkl0, s, 0, 0, 0);
                s = __builtin_amdgcn_mfma_f32_16x16x32_bf16(aql[m][0], bkh0, s, 0, 0, 0);
                s = __builtin_amdgcn_mfma_f32_16x16x32_bf16(aqh[m][1], bkh1, s, 0, 0, 0);
                s = __builtin_amdgcn_mfma_f32_16x16x32_bf16(aqh[m][1], bkl1, s, 0, 0, 0);
                s = __builtin_amdgcn_mfma_f32_16x16x32_bf16(aql[m][1], bkh1, s, 0, 0, 0);
                accs[m][nt] = s * 8.0f;   // * sqrt(head_size), faithful to reference
            }
        }

        if (CAUSAL && kt >= 2 * qb) {
#pragma unroll
            for (int m = 0; m < 2; ++m)
#pragma unroll
                for (int nt = 0; nt < 4; ++nt)
#pragma unroll
                    for (int r = 0; r < 4; ++r) {
                        int qrow = qbase + w * 32 + m * 16 + lg * 4 + r;
                        int kcol = kbase + nt * 16 + lr;
                        if (kcol > qrow) accs[m][nt][r] = -1e30f;
                    }
        }

        // online softmax (row-wise over the 16 lanes holding this row)
#pragma unroll
        for (int m = 0; m < 2; ++m) {
            float alpha[4];
#pragma unroll
            for (int r = 0; r < 4; ++r) {
                float mx = fmaxf(fmaxf(accs[m][0][r], accs[m][1][r]),
                                 fmaxf(accs[m][2][r], accs[m][3][r]));
#pragma unroll
                for (int msk = 1; msk < 16; msk <<= 1) mx = fmaxf(mx, __shfl_xor(mx, msk, 64));
                float mnew = fmaxf(mrow[m][r], mx);
                float sum = 0.0f;
#pragma unroll
                for (int nt = 0; nt < 4; ++nt) {
                    float p = __expf(accs[m][nt][r] - mnew);
                    accs[m][nt][r] = p;
                    sum += p;
                }
#pragma unroll
                for (int msk = 1; msk < 16; msk <<= 1) sum += __shfl_xor(sum, msk, 64);
                alpha[r] = __expf(mrow[m][r] - mnew);
                lsum[m][r] = lsum[m][r] * alpha[r] + sum;
                mrow[m][r] = mnew;
            }
#pragma unroll
            for (int et = 0; et < 4; ++et)
#pragma unroll
                for (int r = 0; r < 4; ++r) acc_o[m][et][r] *= alpha[r];

            // P -> LDS (bf16 hi only; wave-private, no barrier needed)
#pragma unroll
            for (int nt = 0; nt < 4; ++nt)
#pragma unroll
                for (int r = 0; r < 4; ++r)
                    Ph[w][m * 16 + lg * 4 + r][nt * 16 + lr] = (bf16_t)accs[m][nt][r];
        }

        // O += P @ V  (pure bf16)
#pragma unroll
        for (int m = 0; m < 2; ++m) {
            bf16x8 ap0 = *(const bf16x8*)&Ph[w][m * 16 + lr][lg * 8];
            bf16x8 ap1 = *(const bf16x8*)&Ph[w][m * 16 + lr][32 + lg * 8];
#pragma unroll
            for (int et = 0; et < 4; ++et) {
                bf16x8 bv0 = *(const bf16x8*)&Vth[et * 16 + lr][lg * 8];
                bf16x8 bv1 = *(const bf16x8*)&Vth[et * 16 + lr][32 + lg * 8];
                acc_o[m][et] = __builtin_amdgcn_mfma_f32_16x16x32_bf16(ap0, bv0, acc_o[m][et], 0, 0, 0);
                acc_o[m][et] = __builtin_amdgcn_mfma_f32_16x16x32_bf16(ap1, bv1, acc_o[m][et], 0, 0, 0);
            }
        }
    }

#pragma unroll
    for (int m = 0; m < 2; ++m) {
        size_t obase = (size_t)(b * TT + qbase + w * 32 + m * 16) * D + h * HS;
#pragma unroll
        for (int r = 0; r < 4; ++r) {
            float inv = 1.0f / lsum[m][r];
#pragma unroll
            for (int et = 0; et < 4; ++et) {
                float v = acc_o[m][et][r] * inv;
                bf16_t hh = (bf16_t)v;
                size_t idx = obase + (size_t)(lg * 4 + r) * D + et * 16 + lr;
                oh[idx] = hh;
                ol[idx] = (bf16_t)(v - (float)hh);
            }
        }
    }
}

// ---------------------------------------------------------------------------
extern "C" void kernel_launch(void* const* d_in, const int* in_sizes, int n_in,
                              void* d_out, int out_size, void* d_ws, size_t ws_size,
                              hipStream_t stream)
{
    const float* x     = (const float*)d_in[0];
    const float* Wq    = (const float*)d_in[1];
    const float* bq    = (const float*)d_in[2];
    const float* Wk    = (const float*)d_in[3];
    const float* bk    = (const float*)d_in[4];
    const float* Wv    = (const float*)d_in[5];
    const float* bv    = (const float*)d_in[6];
    const float* Wp    = (const float*)d_in[7];
    const float* bp    = (const float*)d_in[8];
    const float* gamma = (const float*)d_in[9];
    const float* W1    = (const float*)d_in[10];
    const float* b1    = (const float*)d_in[11];
    const float* W2    = (const float*)d_in[12];
    const float* b2    = (const float*)d_in[13];
    float* out = (float*)d_out;

    // workspace layout (96 MB):
    //  0..16  : nrm hi/lo (8 MB each); also ao hi/lo (aliased, nrm dead by attn)
    // 16..64  : fused qkv hi (24 MB) + lo (24 MB); h1 hi/lo (32+32) alias 16..80
    // 64..80  : spare (h1 lo tail); bias3072 lives at 64 MB while qkv in flight
    // 80..96  : weight slot (attn: wqkv 12 + wp 4; ffn: W1 16 then W2 16)
    char* base = (char*)d_ws;
    bf16_t* nrmH  = (bf16_t*)(base);
    bf16_t* nrmL  = (bf16_t*)(base + (8u  << 20));
    bf16_t* qkvH  = (bf16_t*)(base + (16u << 20));
    bf16_t* qkvL  = (bf16_t*)(base + (40u << 20));
    float*  bias3 = (float*)(base + (64u << 20));
    bf16_t* h1H   = (bf16_t*)(base + (16u << 20));   // 32 MB
    bf16_t* h1L   = (bf16_t*)(base + (48u << 20));   // 32 MB
    bf16_t* wsl   = (bf16_t*)(base + (80u << 20));   // 16 MB weight slot
    bf16_t* aoH = nrmH, *aoL = nrmL;
    float* abuf = out;   // 'a' lives in d_out, dead before final write
    float* bbuf = out;   // 'b' overwrites 'a' in d_out (a unused after rmsnorm)

    // attention-phase weight slot: wqkv hi [3072][1024], wqkv lo, wp hi, wp lo
    size_t DD = (size_t)D * D;
    bf16_t* wqkvH = wsl;
    bf16_t* wqkvL = wsl + 3 * DD;
    bf16_t* wpH   = wsl + 6 * DD;
    bf16_t* wpL   = wsl + 7 * DD;

    dim3 blk(256);
    dim3 gcvD(D / 64, D / 64);
    dim3 gcv1(D / 64, HF / 64);
    dim3 gcv2(HF / 64, D / 64);
    dim3 gQKV(3 * D / 128, MR / 128);   // 24 x 32 = 768 blocks
    dim3 gP(D / 128, MR / 128);         // 8 x 32 = 256 blocks
    dim3 gF(HF / 128, MR / 128);        // 32 x 32 = 1024 blocks
    dim3 gA(TT / 128, NH, BB);          // 8 x 16 x 4 = 512 blocks

    // ---- a = x + attn(rmsnorm(x), causal=false)
    rmsnorm_kernel<<<MR, blk, 0, stream>>>(x, gamma, nrmH, nrmL);
    concat_bias_kernel<<<12, blk, 0, stream>>>(bq, bk, bv, bias3);
    convw_kernel<<<gcvD, blk, 0, stream>>>(Wq, wqkvH,          wqkvL,          D, D);
    convw_kernel<<<gcvD, blk, 0, stream>>>(Wk, wqkvH + DD,     wqkvL + DD,     D, D);
    convw_kernel<<<gcvD, blk, 0, stream>>>(Wv, wqkvH + 2 * DD, wqkvL + 2 * DD, D, D);
    convw_kernel<<<gcvD, blk, 0, stream>>>(Wp, wpH,            wpL,            D, D);
    gemm_kernel<1, false, false><<<gQKV, blk, 0, stream>>>(nrmH, nrmL, wqkvH, wqkvL, bias3, nullptr, nullptr, qkvH, qkvL, 3 * D, D);
    attn_kernel<false><<<gA, blk, 0, stream>>>(qkvH, qkvL, aoH, aoL);
    gemm_kernel<0, false, true><<<gP, blk, 0, stream>>>(aoH, aoL, wpH, wpL, bp, x, abuf, nullptr, nullptr, D, D);

    // ---- b = x + ffwd(rmsnorm(a))
    rmsnorm_kernel<<<MR, blk, 0, stream>>>(abuf, gamma, nrmH, nrmL);
    convw_kernel<<<gcv1, blk, 0, stream>>>(W1, wsl, wsl + (size_t)HF * D, D, HF);
    gemm_kernel<1, true, false><<<gF, blk, 0, stream>>>(nrmH, nrmL, wsl, wsl + (size_t)HF * D, b1, nullptr, nullptr, h1H, h1L, HF, D);
    convw_kernel<<<gcv2, blk, 0, stream>>>(W2, wsl, wsl + (size_t)D * HF, HF, D);
    gemm_kernel<0, false, true><<<gP, blk, 0, stream>>>(h1H, h1L, wsl, wsl + (size_t)D * HF, b2, x, bbuf, nullptr, nullptr, D, HF);

    // ---- c = b + attn(rmsnorm(b), causal=true)
    rmsnorm_kernel<<<MR, blk, 0, stream>>>(bbuf, gamma, nrmH, nrmL);
    concat_bias_kernel<<<12, blk, 0, stream>>>(bq, bk, bv, bias3);
    convw_kernel<<<gcvD, blk, 0, stream>>>(Wq, wqkvH,          wqkvL,          D, D);
    convw_kernel<<<gcvD, blk, 0, stream>>>(Wk, wqkvH + DD,     wqkvL + DD,     D, D);
    convw_kernel<<<gcvD, blk, 0, stream>>>(Wv, wqkvH + 2 * DD, wqkvL + 2 * DD, D, D);
    convw_kernel<<<gcvD, blk, 0, stream>>>(Wp, wpH,            wpL,            D, D);
    gemm_kernel<1, false, false><<<gQKV, blk, 0, stream>>>(nrmH, nrmL, wqkvH, wqkvL, bias3, nullptr, nullptr, qkvH, qkvL, 3 * D, D);
    attn_kernel<true><<<gA, blk, 0, stream>>>(qkvH, qkvL, aoH, aoL);
    gemm_kernel<0, false, true><<<gP, blk, 0, stream>>>(aoH, aoL, wpH, wpL, bp, bbuf, out, nullptr, nullptr, D, D);
}

// Round 5
// 786.165 us; speedup vs baseline: 2.1944x; 1.0011x over previous
//
#include <hip/hip_runtime.h>
#include <cstdint>
#include <cstddef>

typedef __bf16 bf16_t;
typedef __attribute__((ext_vector_type(8))) __bf16 bf16x8;
typedef __attribute__((ext_vector_type(4))) __bf16 bf16x4;
typedef __attribute__((ext_vector_type(4))) float f32x4;

constexpr int D  = 1024;   // d_model
constexpr int TT = 1024;   // seq len
constexpr int BB = 4;      // batch
constexpr int NH = 16;     // heads
constexpr int HS = 64;     // head size
constexpr int MR = BB * TT; // 4096 rows
constexpr int HF = 4096;   // ffn hidden

__device__ inline void gload_lds16(const bf16_t* g, bf16_t* l)
{
    __builtin_amdgcn_global_load_lds(
        (const __attribute__((address_space(1))) void*)g,
        (__attribute__((address_space(3))) void*)l, 16, 0, 0);
}

// ---------------------------------------------------------------------------
// RMSNorm: f32 in -> bf16 hi/lo planes out. One block (256 thr) per row.
// ---------------------------------------------------------------------------
__global__ __launch_bounds__(256) void rmsnorm_kernel(const float* __restrict__ x,
                                                      const float* __restrict__ gamma,
                                                      bf16_t* __restrict__ oh,
                                                      bf16_t* __restrict__ ol)
{
    int row = blockIdx.x;
    int t   = threadIdx.x;
    const float* xr = x + (size_t)row * D;
    float4 xv = *(const float4*)(xr + t * 4);
    float ss = xv.x * xv.x + xv.y * xv.y + xv.z * xv.z + xv.w * xv.w;
#pragma unroll
    for (int m = 1; m < 64; m <<= 1) ss += __shfl_xor(ss, m, 64);
    __shared__ float part[4];
    if ((t & 63) == 0) part[t >> 6] = ss;
    __syncthreads();
    float tot   = part[0] + part[1] + part[2] + part[3];
    float scale = rsqrtf(tot * (1.0f / D) + 1e-6f);
    float4 gv = *(const float4*)(gamma + t * 4);
    float vals[4] = {xv.x * scale * gv.x, xv.y * scale * gv.y,
                     xv.z * scale * gv.z, xv.w * scale * gv.w};
    bf16x4 vh, vl;
#pragma unroll
    for (int j = 0; j < 4; ++j) {
        bf16_t h = (bf16_t)vals[j];
        vh[j] = h;
        vl[j] = (bf16_t)(vals[j] - (float)h);
    }
    *(bf16x4*)(oh + (size_t)row * D + t * 4) = vh;
    *(bf16x4*)(ol + (size_t)row * D + t * 4) = vl;
}

// ---------------------------------------------------------------------------
// concat 3x [1024] f32 biases into one [3072] buffer
// ---------------------------------------------------------------------------
__global__ __launch_bounds__(256) void concat_bias_kernel(const float* __restrict__ a,
                                                          const float* __restrict__ b,
                                                          const float* __restrict__ c,
                                                          float* __restrict__ o)
{
    int i = blockIdx.x * 256 + threadIdx.x;
    o[i] = i < 1024 ? a[i] : (i < 2048 ? b[i - 1024] : c[i - 2048]);
}

// ---------------------------------------------------------------------------
// Weight convert: W f32 [K][N] -> dH/dL bf16 [N][K] planes (transposed).
// 64x64 tile via padded LDS transpose. Grid (K/64, N/64), 256 thr.
// ---------------------------------------------------------------------------
__global__ __launch_bounds__(256) void convw_kernel(const float* __restrict__ W,
                                                    bf16_t* __restrict__ dH,
                                                    bf16_t* __restrict__ dL,
                                                    int K, int N)
{
    __shared__ float sld[64][65];
    int t = threadIdx.x;
    int k0 = blockIdx.x * 64, n0 = blockIdx.y * 64;
    int kr = t >> 4, nc = (t & 15) * 4;
#pragma unroll
    for (int p = 0; p < 4; ++p) {
        int k = p * 16 + kr;
        float4 v = *(const float4*)(W + (size_t)(k0 + k) * N + n0 + nc);
        sld[k][nc] = v.x; sld[k][nc + 1] = v.y; sld[k][nc + 2] = v.z; sld[k][nc + 3] = v.w;
    }
    __syncthreads();
    int n = t >> 2, kh = (t & 3) * 16;
    bf16x8 h0, l0, h1, l1;
#pragma unroll
    for (int j = 0; j < 8; ++j) {
        float v = sld[kh + j][n];
        bf16_t h = (bf16_t)v;
        h0[j] = h; l0[j] = (bf16_t)(v - (float)h);
    }
#pragma unroll
    for (int j = 0; j < 8; ++j) {
        float v = sld[kh + 8 + j][n];
        bf16_t h = (bf16_t)v;
        h1[j] = h; l1[j] = (bf16_t)(v - (float)h);
    }
    size_t o = (size_t)(n0 + n) * K + k0 + kh;
    *(bf16x8*)(dH + o)     = h0;
    *(bf16x8*)(dH + o + 8) = h1;
    *(bf16x8*)(dL + o)     = l0;
    *(bf16x8*)(dL + o + 8) = l1;
}

// ---------------------------------------------------------------------------
// Split-precision GEMM, 128x128 tile, BK=32, 4 waves (64x64 each, 4x4 frags).
// A hi/lo bf16 [M][K]; W hi/lo bf16 [N][K] (pre-transposed). 3 MFMAs per pair.
// global_load_lds(16B) staging into linear LDS, XOR-swizzled source+read.
// OUTM: 0 = f32 out, 1 = bf16 hi/lo planes out.
// ---------------------------------------------------------------------------
template<int OUTM, bool RELU, bool RESID>
__global__ __launch_bounds__(256, 2) void gemm_kernel(
    const bf16_t* __restrict__ Ahp, const bf16_t* __restrict__ Alp,
    const bf16_t* __restrict__ Whp, const bf16_t* __restrict__ Wlp,
    const float* __restrict__ bias, const float* resid,
    float* outf, bf16_t* __restrict__ outh, bf16_t* __restrict__ outl,
    int N, int K)
{
    __shared__ bf16_t sA[2][128][32];   // [hi/lo][m][k], linear (gload_lds dest)
    __shared__ bf16_t sW[2][128][32];   // [hi/lo][n][k]

    int t = threadIdx.x;
    int l = t & 63, w = t >> 6;
    int lr = l & 15, lg = l >> 4;

    // XCD-aware block swizzle (all grids have nwg % 8 == 0)
    int gx  = gridDim.x;
    int nwg = gx * gridDim.y;
    int bid = blockIdx.y * gx + blockIdx.x;
    int s   = (bid & 7) * (nwg >> 3) + (bid >> 3);
    int nb  = s % gx, mb = s / gx;
    int m0 = mb * 128, n0 = nb * 128;
    int wr = (w >> 1) * 64, wc = (w & 1) * 64;

    f32x4 acc[4][4] = {};

    // staging: wave w covers rows [w*32, w*32+32) of each plane, 2 chunks x16 rows
    int srow = (l >> 2);      // 0..15 within chunk
    int sch  = l & 3;         // 16B slot within 64B row

    for (int kk = 0; kk < K; kk += 32) {
        __syncthreads();
#pragma unroll
        for (int c = 0; c < 2; ++c) {
            int rbase = w * 32 + c * 16;
            int row = rbase + srow;
            int f = (row >> 1) & 3;
            size_t goff = (size_t)row * K + kk + (size_t)((sch ^ f)) * 8;
            gload_lds16(Ahp + (size_t)m0 * K + goff, &sA[0][rbase][0]);
            gload_lds16(Alp + (size_t)m0 * K + goff, &sA[1][rbase][0]);
            gload_lds16(Whp + (size_t)n0 * K + goff, &sW[0][rbase][0]);
            gload_lds16(Wlp + (size_t)n0 * K + goff, &sW[1][rbase][0]);
        }
        __syncthreads();

        bf16x8 a0[4], a1[4], b0[4], b1[4];
#pragma unroll
        for (int m = 0; m < 4; ++m) {
            int row = wr + m * 16 + lr;
            int sl = lg ^ ((row >> 1) & 3);
            a0[m] = *(const bf16x8*)&sA[0][row][sl * 8];
            a1[m] = *(const bf16x8*)&sA[1][row][sl * 8];
        }
#pragma unroll
        for (int n = 0; n < 4; ++n) {
            int row = wc + n * 16 + lr;
            int sl = lg ^ ((row >> 1) & 3);
            b0[n] = *(const bf16x8*)&sW[0][row][sl * 8];
            b1[n] = *(const bf16x8*)&sW[1][row][sl * 8];
        }
        // hh pass, then hl, then lh: dependent ops on same acc are 16 apart
#pragma unroll
        for (int m = 0; m < 4; ++m)
#pragma unroll
            for (int n = 0; n < 4; ++n)
                acc[m][n] = __builtin_amdgcn_mfma_f32_16x16x32_bf16(a0[m], b0[n], acc[m][n], 0, 0, 0);
#pragma unroll
        for (int m = 0; m < 4; ++m)
#pragma unroll
            for (int n = 0; n < 4; ++n)
                acc[m][n] = __builtin_amdgcn_mfma_f32_16x16x32_bf16(a0[m], b1[n], acc[m][n], 0, 0, 0);
#pragma unroll
        for (int m = 0; m < 4; ++m)
#pragma unroll
            for (int n = 0; n < 4; ++n)
                acc[m][n] = __builtin_amdgcn_mfma_f32_16x16x32_bf16(a1[m], b0[n], acc[m][n], 0, 0, 0);
    }

#pragma unroll
    for (int m = 0; m < 4; ++m) {
#pragma unroll
        for (int n = 0; n < 4; ++n) {
            int col = n0 + wc + n * 16 + lr;
            float bv = bias[col];
#pragma unroll
            for (int r = 0; r < 4; ++r) {
                int row = m0 + wr + m * 16 + lg * 4 + r;
                float v = acc[m][n][r] + bv;
                if (RELU)  v = (v >= 0.0f) ? v : 0.1f * v;
                if (RESID) v += resid[(size_t)row * N + col];
                if (OUTM == 0) {
                    outf[(size_t)row * N + col] = v;
                } else {
                    bf16_t h = (bf16_t)v;
                    outh[(size_t)row * N + col] = h;
                    outl[(size_t)row * N + col] = (bf16_t)(v - (float)h);
                }
            }
        }
    }
}

// ---------------------------------------------------------------------------
// Flash attention from fused QKV planes (row stride 3D; q/k/v at col 0/D/2D).
// Block = 256 thr (4 waves), 128 q-rows per block (32/wave).
// QK^T split-precision (3 MFMA/pair); PV pure bf16-hi (P in [0,1], V post-
// softmax: bf16 rounding ~2e-3 abs, negligible). V staged hi-only, pad 70.
// ---------------------------------------------------------------------------
template<bool CAUSAL>
__global__ __launch_bounds__(256, 2) void attn_kernel(
    const bf16_t* __restrict__ qkvH, const bf16_t* __restrict__ qkvL,
    bf16_t* __restrict__ oh, bf16_t* __restrict__ ol)
{
    __shared__ bf16_t Vth[64][70];     // [e][kk] hi, pad 70 (~2-way banks)
    __shared__ bf16_t Ph[4][32][70];   // per-wave [qrow][kk] hi

    int tid = threadIdx.x;
    int qb = blockIdx.x, h = blockIdx.y, b = blockIdx.z;
    int l = tid & 63, w = tid >> 6;
    int lr = l & 15, lg = l >> 4;
    int qbase = qb * 128;
    const int QS = 3 * D;

    // Q frags: 32 rows per wave (2 x 16-row frags), hi/lo, both k-halves
    bf16x8 aqh[2][2], aql[2][2];
#pragma unroll
    for (int m = 0; m < 2; ++m) {
        size_t qoff = (size_t)(b * TT + qbase + w * 32 + m * 16 + lr) * QS + h * HS;
#pragma unroll
        for (int c = 0; c < 2; ++c) {
            aqh[m][c] = *(const bf16x8*)(qkvH + qoff + c * 32 + lg * 8);
            aql[m][c] = *(const bf16x8*)(qkvL + qoff + c * 32 + lg * 8);
        }
    }

    float mrow[2][4], lsum[2][4];
    f32x4 acc_o[2][4] = {};
#pragma unroll
    for (int m = 0; m < 2; ++m)
#pragma unroll
        for (int r = 0; r < 4; ++r) { mrow[m][r] = -1e30f; lsum[m][r] = 0.0f; }

    int ktmax = CAUSAL ? (2 * qb + 1) : (TT / 64 - 1);
    for (int kt = 0; kt <= ktmax; ++kt) {
        int kbase = kt * 64;
        __syncthreads();
        // stage V tile (hi only) transposed: Vth[e][kk]
#pragma unroll
        for (int rr = 0; rr < 2; ++rr) {
            int vrow = (tid >> 3) + rr * 32;
            int vcol = (tid & 7) * 8;
            size_t voff = (size_t)(b * TT + kbase + vrow) * QS + 2 * D + h * HS + vcol;
            bf16x8 vv = *(const bf16x8*)(qkvH + voff);
#pragma unroll
            for (int j = 0; j < 8; ++j) Vth[vcol + j][vrow] = vv[j];
        }
        __syncthreads();

        // S = Q K^T  (32 q-rows x 64 k-cols per wave), split 3-MFMA
        f32x4 accs[2][4];
        size_t koff = (size_t)(b * TT + kbase + lr) * QS + D + h * HS;
#pragma unroll
        for (int nt = 0; nt < 4; ++nt) {
            size_t ko = koff + (size_t)(nt * 16) * QS;
            bf16x8 bkh0 = *(const bf16x8*)(qkvH + ko + lg * 8);
            bf16x8 bkl0 = *(const bf16x8*)(qkvL + ko + lg * 8);
            bf16x8 bkh1 = *(const bf16x8*)(qkvH + ko + 32 + lg * 8);
            bf16x8 bkl1 = *(const bf16x8*)(qkvL + ko + 32 + lg * 8);
#pragma unroll
            for (int m = 0; m < 2; ++m) {
                f32x4 s = {};
                s = __builtin_amdgcn_mfma_f32_16x16x32_bf16(aqh[m][0], bkh0, s, 0, 0, 0);
                s = __builtin_amdgcn_mfma_f32_16x16x32_bf16(aqh[m][0], bkl0, s, 0, 0, 0);
                s = __builtin_amdgcn_mfma_f32_16x16x32_bf16(aql[m][0], bkh0, s, 0, 0, 0);
                s = __builtin_amdgcn_mfma_f32_16x16x32_bf16(aqh[m][1], bkh1, s, 0, 0, 0);
                s = __builtin_amdgcn_mfma_f32_16x16x32_bf16(aqh[m][1], bkl1, s, 0, 0, 0);
                s = __builtin_amdgcn_mfma_f32_16x16x32_bf16(aql[m][1], bkh1, s, 0, 0, 0);
                accs[m][nt] = s * 8.0f;   // * sqrt(head_size), faithful to reference
            }
        }

        if (CAUSAL && kt >= 2 * qb) {
#pragma unroll
            for (int m = 0; m < 2; ++m)
#pragma unroll
                for (int nt = 0; nt < 4; ++nt)
#pragma unroll
                    for (int r = 0; r < 4; ++r) {
                        int qrow = qbase + w * 32 + m * 16 + lg * 4 + r;
                        int kcol = kbase + nt * 16 + lr;
                        if (kcol > qrow) accs[m][nt][r] = -1e30f;
                    }
        }

        // online softmax (row-wise over the 16 lanes holding this row)
#pragma unroll
        for (int m = 0; m < 2; ++m) {
            float alpha[4];
#pragma unroll
            for (int r = 0; r < 4; ++r) {
                float mx = fmaxf(fmaxf(accs[m][0][r], accs[m][1][r]),
                                 fmaxf(accs[m][2][r], accs[m][3][r]));
#pragma unroll
                for (int msk = 1; msk < 16; msk <<= 1) mx = fmaxf(mx, __shfl_xor(mx, msk, 64));
                float mnew = fmaxf(mrow[m][r], mx);
                float sum = 0.0f;
#pragma unroll
                for (int nt = 0; nt < 4; ++nt) {
                    float p = __expf(accs[m][nt][r] - mnew);
                    accs[m][nt][r] = p;
                    sum += p;
                }
#pragma unroll
                for (int msk = 1; msk < 16; msk <<= 1) sum += __shfl_xor(sum, msk, 64);
                alpha[r] = __expf(mrow[m][r] - mnew);
                lsum[m][r] = lsum[m][r] * alpha[r] + sum;
                mrow[m][r] = mnew;
            }
#pragma unroll
            for (int et = 0; et < 4; ++et)
#pragma unroll
                for (int r = 0; r < 4; ++r) acc_o[m][et][r] *= alpha[r];

            // P -> LDS (bf16 hi only; wave-private, no barrier needed)
#pragma unroll
            for (int nt = 0; nt < 4; ++nt)
#pragma unroll
                for (int r = 0; r < 4; ++r)
                    Ph[w][m * 16 + lg * 4 + r][nt * 16 + lr] = (bf16_t)accs[m][nt][r];
        }

        // O += P @ V  (pure bf16)
#pragma unroll
        for (int m = 0; m < 2; ++m) {
            bf16x8 ap0 = *(const bf16x8*)&Ph[w][m * 16 + lr][lg * 8];
            bf16x8 ap1 = *(const bf16x8*)&Ph[w][m * 16 + lr][32 + lg * 8];
#pragma unroll
            for (int et = 0; et < 4; ++et) {
                bf16x8 bv0 = *(const bf16x8*)&Vth[et * 16 + lr][lg * 8];
                bf16x8 bv1 = *(const bf16x8*)&Vth[et * 16 + lr][32 + lg * 8];
                acc_o[m][et] = __builtin_amdgcn_mfma_f32_16x16x32_bf16(ap0, bv0, acc_o[m][et], 0, 0, 0);
                acc_o[m][et] = __builtin_amdgcn_mfma_f32_16x16x32_bf16(ap1, bv1, acc_o[m][et], 0, 0, 0);
            }
        }
    }

#pragma unroll
    for (int m = 0; m < 2; ++m) {
        size_t obase = (size_t)(b * TT + qbase + w * 32 + m * 16) * D + h * HS;
#pragma unroll
        for (int r = 0; r < 4; ++r) {
            float inv = 1.0f / lsum[m][r];
#pragma unroll
            for (int et = 0; et < 4; ++et) {
                float v = acc_o[m][et][r] * inv;
                bf16_t hh = (bf16_t)v;
                size_t idx = obase + (size_t)(lg * 4 + r) * D + et * 16 + lr;
                oh[idx] = hh;
                ol[idx] = (bf16_t)(v - (float)hh);
            }
        }
    }
}

// ---------------------------------------------------------------------------
extern "C" void kernel_launch(void* const* d_in, const int* in_sizes, int n_in,
                              void* d_out, int out_size, void* d_ws, size_t ws_size,
                              hipStream_t stream)
{
    const float* x     = (const float*)d_in[0];
    const float* Wq    = (const float*)d_in[1];
    const float* bq    = (const float*)d_in[2];
    const float* Wk    = (const float*)d_in[3];
    const float* bk    = (const float*)d_in[4];
    const float* Wv    = (const float*)d_in[5];
    const float* bv    = (const float*)d_in[6];
    const float* Wp    = (const float*)d_in[7];
    const float* bp    = (const float*)d_in[8];
    const float* gamma = (const float*)d_in[9];
    const float* W1    = (const float*)d_in[10];
    const float* b1    = (const float*)d_in[11];
    const float* W2    = (const float*)d_in[12];
    const float* b2    = (const float*)d_in[13];
    float* out = (float*)d_out;

    // workspace layout (96 MB):
    //  0..16  : nrm hi/lo (8 MB each); also ao hi/lo (aliased, nrm dead by attn)
    // 16..64  : fused qkv hi (24 MB) + lo (24 MB); h1 hi/lo (32+32) alias 16..80
    // 64..80  : spare (h1 lo tail); bias3072 lives at 64 MB while qkv in flight
    // 80..96  : weight slot (attn: wqkv 12 + wp 4; ffn: W1 16 then W2 16)
    char* base = (char*)d_ws;
    bf16_t* nrmH  = (bf16_t*)(base);
    bf16_t* nrmL  = (bf16_t*)(base + (8u  << 20));
    bf16_t* qkvH  = (bf16_t*)(base + (16u << 20));
    bf16_t* qkvL  = (bf16_t*)(base + (40u << 20));
    float*  bias3 = (float*)(base + (64u << 20));
    bf16_t* h1H   = (bf16_t*)(base + (16u << 20));   // 32 MB
    bf16_t* h1L   = (bf16_t*)(base + (48u << 20));   // 32 MB
    bf16_t* wsl   = (bf16_t*)(base + (80u << 20));   // 16 MB weight slot
    bf16_t* aoH = nrmH, *aoL = nrmL;
    float* abuf = out;   // 'a' lives in d_out, dead before final write
    float* bbuf = out;   // 'b' overwrites 'a' in d_out (a unused after rmsnorm)

    // attention-phase weight slot: wqkv hi [3072][1024], wqkv lo, wp hi, wp lo
    size_t DD = (size_t)D * D;
    bf16_t* wqkvH = wsl;
    bf16_t* wqkvL = wsl + 3 * DD;
    bf16_t* wpH   = wsl + 6 * DD;
    bf16_t* wpL   = wsl + 7 * DD;

    dim3 blk(256);
    dim3 gcvD(D / 64, D / 64);
    dim3 gcv1(D / 64, HF / 64);
    dim3 gcv2(HF / 64, D / 64);
    dim3 gQKV(3 * D / 128, MR / 128);   // 24 x 32 = 768 blocks
    dim3 gP(D / 128, MR / 128);         // 8 x 32 = 256 blocks
    dim3 gF(HF / 128, MR / 128);        // 32 x 32 = 1024 blocks
    dim3 gA(TT / 128, NH, BB);          // 8 x 16 x 4 = 512 blocks

    // ---- a = x + attn(rmsnorm(x), causal=false)
    rmsnorm_kernel<<<MR, blk, 0, stream>>>(x, gamma, nrmH, nrmL);
    concat_bias_kernel<<<12, blk, 0, stream>>>(bq, bk, bv, bias3);
    convw_kernel<<<gcvD, blk, 0, stream>>>(Wq, wqkvH,          wqkvL,          D, D);
    convw_kernel<<<gcvD, blk, 0, stream>>>(Wk, wqkvH + DD,     wqkvL + DD,     D, D);
    convw_kernel<<<gcvD, blk, 0, stream>>>(Wv, wqkvH + 2 * DD, wqkvL + 2 * DD, D, D);
    convw_kernel<<<gcvD, blk, 0, stream>>>(Wp, wpH,            wpL,            D, D);
    gemm_kernel<1, false, false><<<gQKV, blk, 0, stream>>>(nrmH, nrmL, wqkvH, wqkvL, bias3, nullptr, nullptr, qkvH, qkvL, 3 * D, D);
    attn_kernel<false><<<gA, blk, 0, stream>>>(qkvH, qkvL, aoH, aoL);
    gemm_kernel<0, false, true><<<gP, blk, 0, stream>>>(aoH, aoL, wpH, wpL, bp, x, abuf, nullptr, nullptr, D, D);

    // ---- b = x + ffwd(rmsnorm(a))
    rmsnorm_kernel<<<MR, blk, 0, stream>>>(abuf, gamma, nrmH, nrmL);
    convw_kernel<<<gcv1, blk, 0, stream>>>(W1, wsl, wsl + (size_t)HF * D, D, HF);
    gemm_kernel<1, true, false><<<gF, blk, 0, stream>>>(nrmH, nrmL, wsl, wsl + (size_t)HF * D, b1, nullptr, nullptr, h1H, h1L, HF, D);
    convw_kernel<<<gcv2, blk, 0, stream>>>(W2, wsl, wsl + (size_t)D * HF, HF, D);
    gemm_kernel<0, false, true><<<gP, blk, 0, stream>>>(h1H, h1L, wsl, wsl + (size_t)D * HF, b2, x, bbuf, nullptr, nullptr, D, HF);

    // ---- c = b + attn(rmsnorm(b), causal=true)
    rmsnorm_kernel<<<MR, blk, 0, stream>>>(bbuf, gamma, nrmH, nrmL);
    concat_bias_kernel<<<12, blk, 0, stream>>>(bq, bk, bv, bias3);
    convw_kernel<<<gcvD, blk, 0, stream>>>(Wq, wqkvH,          wqkvL,          D, D);
    convw_kernel<<<gcvD, blk, 0, stream>>>(Wk, wqkvH + DD,     wqkvL + DD,     D, D);
    convw_kernel<<<gcvD, blk, 0, stream>>>(Wv, wqkvH + 2 * DD, wqkvL + 2 * DD, D, D);
    convw_kernel<<<gcvD, blk, 0, stream>>>(Wp, wpH,            wpL,            D, D);
    gemm_kernel<1, false, false><<<gQKV, blk, 0, stream>>>(nrmH, nrmL, wqkvH, wqkvL, bias3, nullptr, nullptr, qkvH, qkvL, 3 * D, D);
    attn_kernel<true><<<gA, blk, 0, stream>>>(qkvH, qkvL, aoH, aoL);
    gemm_kernel<0, false, true><<<gP, blk, 0, stream>>>(aoH, aoL, wpH, wpL, bp, bbuf, out, nullptr, nullptr, D, D);
}

// Round 6
// 726.686 us; speedup vs baseline: 2.3740x; 1.0819x over previous
//
#include <hip/hip_runtime.h>
#include <cstdint>
#include <cstddef>

typedef __bf16 bf16_t;
typedef __attribute__((ext_vector_type(8))) __bf16 bf16x8;
typedef __attribute__((ext_vector_type(4))) __bf16 bf16x4;
typedef __attribute__((ext_vector_type(4))) float f32x4;

constexpr int D  = 1024;   // d_model
constexpr int TT = 1024;   // seq len
constexpr int BB = 4;      // batch
constexpr int NH = 16;     // heads
constexpr int HS = 64;     // head size
constexpr int MR = BB * TT; // 4096 rows
constexpr int HF = 4096;   // ffn hidden

__device__ inline void gload_lds16(const bf16_t* g, bf16_t* l)
{
    __builtin_amdgcn_global_load_lds(
        (const __attribute__((address_space(1))) void*)g,
        (__attribute__((address_space(3))) void*)l, 16, 0, 0);
}

// ---------------------------------------------------------------------------
// RMSNorm: f32 in -> bf16 hi/lo planes out. One block (256 thr) per row.
// ---------------------------------------------------------------------------
__global__ __launch_bounds__(256) void rmsnorm_kernel(const float* __restrict__ x,
                                                      const float* __restrict__ gamma,
                                                      bf16_t* __restrict__ oh,
                                                      bf16_t* __restrict__ ol)
{
    int row = blockIdx.x;
    int t   = threadIdx.x;
    const float* xr = x + (size_t)row * D;
    float4 xv = *(const float4*)(xr + t * 4);
    float ss = xv.x * xv.x + xv.y * xv.y + xv.z * xv.z + xv.w * xv.w;
#pragma unroll
    for (int m = 1; m < 64; m <<= 1) ss += __shfl_xor(ss, m, 64);
    __shared__ float part[4];
    if ((t & 63) == 0) part[t >> 6] = ss;
    __syncthreads();
    float tot   = part[0] + part[1] + part[2] + part[3];
    float scale = rsqrtf(tot * (1.0f / D) + 1e-6f);
    float4 gv = *(const float4*)(gamma + t * 4);
    float vals[4] = {xv.x * scale * gv.x, xv.y * scale * gv.y,
                     xv.z * scale * gv.z, xv.w * scale * gv.w};
    bf16x4 vh, vl;
#pragma unroll
    for (int j = 0; j < 4; ++j) {
        bf16_t h = (bf16_t)vals[j];
        vh[j] = h;
        vl[j] = (bf16_t)(vals[j] - (float)h);
    }
    *(bf16x4*)(oh + (size_t)row * D + t * 4) = vh;
    *(bf16x4*)(ol + (size_t)row * D + t * 4) = vl;
}

// ---------------------------------------------------------------------------
// concat 3x [1024] f32 biases into one [3072] buffer
// ---------------------------------------------------------------------------
__global__ __launch_bounds__(256) void concat_bias_kernel(const float* __restrict__ a,
                                                          const float* __restrict__ b,
                                                          const float* __restrict__ c,
                                                          float* __restrict__ o)
{
    int i = blockIdx.x * 256 + threadIdx.x;
    o[i] = i < 1024 ? a[i] : (i < 2048 ? b[i - 1024] : c[i - 2048]);
}

// ---------------------------------------------------------------------------
// Weight convert: W f32 [K][N] -> dH/dL bf16 [N][K] planes (transposed).
// 64x64 tile via padded LDS transpose. Grid (K/64, N/64), 256 thr.
// ---------------------------------------------------------------------------
__global__ __launch_bounds__(256) void convw_kernel(const float* __restrict__ W,
                                                    bf16_t* __restrict__ dH,
                                                    bf16_t* __restrict__ dL,
                                                    int K, int N)
{
    __shared__ float sld[64][65];
    int t = threadIdx.x;
    int k0 = blockIdx.x * 64, n0 = blockIdx.y * 64;
    int kr = t >> 4, nc = (t & 15) * 4;
#pragma unroll
    for (int p = 0; p < 4; ++p) {
        int k = p * 16 + kr;
        float4 v = *(const float4*)(W + (size_t)(k0 + k) * N + n0 + nc);
        sld[k][nc] = v.x; sld[k][nc + 1] = v.y; sld[k][nc + 2] = v.z; sld[k][nc + 3] = v.w;
    }
    __syncthreads();
    int n = t >> 2, kh = (t & 3) * 16;
    bf16x8 h0, l0, h1, l1;
#pragma unroll
    for (int j = 0; j < 8; ++j) {
        float v = sld[kh + j][n];
        bf16_t h = (bf16_t)v;
        h0[j] = h; l0[j] = (bf16_t)(v - (float)h);
    }
#pragma unroll
    for (int j = 0; j < 8; ++j) {
        float v = sld[kh + 8 + j][n];
        bf16_t h = (bf16_t)v;
        h1[j] = h; l1[j] = (bf16_t)(v - (float)h);
    }
    size_t o = (size_t)(n0 + n) * K + k0 + kh;
    *(bf16x8*)(dH + o)     = h0;
    *(bf16x8*)(dH + o + 8) = h1;
    *(bf16x8*)(dL + o)     = l0;
    *(bf16x8*)(dL + o + 8) = l1;
}

// ---------------------------------------------------------------------------
// Split-precision GEMM, 128xTN tile (TN = 64 or 128), BK=32, 4 waves.
// TN=128: waves own 64x64 (4x4 frags). TN=64: waves own 64x32 (4x2 frags) --
// used for N=1024 GEMMs to double grid size (256 -> 512 blocks).
// A hi/lo bf16 [M][K]; W hi/lo bf16 [N][K] (pre-transposed). 3 MFMAs per pair.
// global_load_lds(16B) staging into linear LDS, XOR-swizzled source+read.
// OUTM: 0 = f32 out, 1 = bf16 hi/lo planes out.
// ---------------------------------------------------------------------------
template<int TN, int OUTM, bool RELU, bool RESID>
__global__ __launch_bounds__(256, 2) void gemm_kernel(
    const bf16_t* __restrict__ Ahp, const bf16_t* __restrict__ Alp,
    const bf16_t* __restrict__ Whp, const bf16_t* __restrict__ Wlp,
    const float* __restrict__ bias, const float* resid,
    float* outf, bf16_t* __restrict__ outh, bf16_t* __restrict__ outl,
    int N, int K)
{
    constexpr int NF = TN / 32;          // n-frags per wave
    __shared__ bf16_t sA[2][128][32];    // [hi/lo][m][k], linear (gload_lds dest)
    __shared__ bf16_t sW[2][TN][32];     // [hi/lo][n][k]

    int t = threadIdx.x;
    int l = t & 63, w = t >> 6;
    int lr = l & 15, lg = l >> 4;

    // XCD-aware block swizzle (all grids have nwg % 8 == 0)
    int gx  = gridDim.x;
    int nwg = gx * gridDim.y;
    int bid = blockIdx.y * gx + blockIdx.x;
    int s   = (bid & 7) * (nwg >> 3) + (bid >> 3);
    int nb  = s % gx, mb = s / gx;
    int m0 = mb * 128, n0 = nb * TN;
    int wr = (w >> 1) * 64, wc = (w & 1) * (TN / 2);

    f32x4 acc[4][NF] = {};

    int srow = (l >> 2);      // 0..15 within chunk
    int sch  = l & 3;         // 16B slot within 64B row

    for (int kk = 0; kk < K; kk += 32) {
        __syncthreads();
        // A planes: 128 rows = 4 waves x 2 chunks x 16
#pragma unroll
        for (int c = 0; c < 2; ++c) {
            int rbase = w * 32 + c * 16;
            int row = rbase + srow;
            int f = (row >> 1) & 3;
            size_t goff = (size_t)row * K + kk + (size_t)((sch ^ f)) * 8;
            gload_lds16(Ahp + (size_t)m0 * K + goff, &sA[0][rbase][0]);
            gload_lds16(Alp + (size_t)m0 * K + goff, &sA[1][rbase][0]);
        }
        // W planes: TN rows = 4 waves x (TN/64) chunks x 16
#pragma unroll
        for (int c = 0; c < TN / 64; ++c) {
            int rbase = w * (TN / 4) + c * 16;
            int row = rbase + srow;
            int f = (row >> 1) & 3;
            size_t goff = (size_t)row * K + kk + (size_t)((sch ^ f)) * 8;
            gload_lds16(Whp + (size_t)n0 * K + goff, &sW[0][rbase][0]);
            gload_lds16(Wlp + (size_t)n0 * K + goff, &sW[1][rbase][0]);
        }
        __syncthreads();

        bf16x8 a0[4], a1[4], b0[NF], b1[NF];
#pragma unroll
        for (int m = 0; m < 4; ++m) {
            int row = wr + m * 16 + lr;
            int sl = lg ^ ((row >> 1) & 3);
            a0[m] = *(const bf16x8*)&sA[0][row][sl * 8];
            a1[m] = *(const bf16x8*)&sA[1][row][sl * 8];
        }
#pragma unroll
        for (int n = 0; n < NF; ++n) {
            int row = wc + n * 16 + lr;
            int sl = lg ^ ((row >> 1) & 3);
            b0[n] = *(const bf16x8*)&sW[0][row][sl * 8];
            b1[n] = *(const bf16x8*)&sW[1][row][sl * 8];
        }
        // hh pass, then hl, then lh: dependent ops on same acc are spaced apart
#pragma unroll
        for (int m = 0; m < 4; ++m)
#pragma unroll
            for (int n = 0; n < NF; ++n)
                acc[m][n] = __builtin_amdgcn_mfma_f32_16x16x32_bf16(a0[m], b0[n], acc[m][n], 0, 0, 0);
#pragma unroll
        for (int m = 0; m < 4; ++m)
#pragma unroll
            for (int n = 0; n < NF; ++n)
                acc[m][n] = __builtin_amdgcn_mfma_f32_16x16x32_bf16(a0[m], b1[n], acc[m][n], 0, 0, 0);
#pragma unroll
        for (int m = 0; m < 4; ++m)
#pragma unroll
            for (int n = 0; n < NF; ++n)
                acc[m][n] = __builtin_amdgcn_mfma_f32_16x16x32_bf16(a1[m], b0[n], acc[m][n], 0, 0, 0);
    }

#pragma unroll
    for (int m = 0; m < 4; ++m) {
#pragma unroll
        for (int n = 0; n < NF; ++n) {
            int col = n0 + wc + n * 16 + lr;
            float bv = bias[col];
#pragma unroll
            for (int r = 0; r < 4; ++r) {
                int row = m0 + wr + m * 16 + lg * 4 + r;
                float v = acc[m][n][r] + bv;
                if (RELU)  v = (v >= 0.0f) ? v : 0.1f * v;
                if (RESID) v += resid[(size_t)row * N + col];
                if (OUTM == 0) {
                    outf[(size_t)row * N + col] = v;
                } else {
                    bf16_t h = (bf16_t)v;
                    outh[(size_t)row * N + col] = h;
                    outl[(size_t)row * N + col] = (bf16_t)(v - (float)h);
                }
            }
        }
    }
}

// ---------------------------------------------------------------------------
// Flash attention from fused QKV planes (row stride 3D; q/k/v at col 0/D/2D).
// Block = 256 thr (4 waves), 128 q-rows per block (32/wave).
// QK^T split-precision (3 MFMA/pair); PV pure bf16-hi. V staged hi-only.
// ---------------------------------------------------------------------------
template<bool CAUSAL>
__global__ __launch_bounds__(256, 2) void attn_kernel(
    const bf16_t* __restrict__ qkvH, const bf16_t* __restrict__ qkvL,
    bf16_t* __restrict__ oh, bf16_t* __restrict__ ol)
{
    __shared__ bf16_t Vth[64][70];     // [e][kk] hi, pad 70 (~2-way banks)
    __shared__ bf16_t Ph[4][32][70];   // per-wave [qrow][kk] hi

    int tid = threadIdx.x;
    int qb = blockIdx.x, h = blockIdx.y, b = blockIdx.z;
    int l = tid & 63, w = tid >> 6;
    int lr = l & 15, lg = l >> 4;
    int qbase = qb * 128;
    const int QS = 3 * D;

    // Q frags: 32 rows per wave (2 x 16-row frags), hi/lo, both k-halves
    bf16x8 aqh[2][2], aql[2][2];
#pragma unroll
    for (int m = 0; m < 2; ++m) {
        size_t qoff = (size_t)(b * TT + qbase + w * 32 + m * 16 + lr) * QS + h * HS;
#pragma unroll
        for (int c = 0; c < 2; ++c) {
            aqh[m][c] = *(const bf16x8*)(qkvH + qoff + c * 32 + lg * 8);
            aql[m][c] = *(const bf16x8*)(qkvL + qoff + c * 32 + lg * 8);
        }
    }

    float mrow[2][4], lsum[2][4];
    f32x4 acc_o[2][4] = {};
#pragma unroll
    for (int m = 0; m < 2; ++m)
#pragma unroll
        for (int r = 0; r < 4; ++r) { mrow[m][r] = -1e30f; lsum[m][r] = 0.0f; }

    int ktmax = CAUSAL ? (2 * qb + 1) : (TT / 64 - 1);
    for (int kt = 0; kt <= ktmax; ++kt) {
        int kbase = kt * 64;
        __syncthreads();
        // stage V tile (hi only) transposed: Vth[e][kk]
#pragma unroll
        for (int rr = 0; rr < 2; ++rr) {
            int vrow = (tid >> 3) + rr * 32;
            int vcol = (tid & 7) * 8;
            size_t voff = (size_t)(b * TT + kbase + vrow) * QS + 2 * D + h * HS + vcol;
            bf16x8 vv = *(const bf16x8*)(qkvH + voff);
#pragma unroll
            for (int j = 0; j < 8; ++j) Vth[vcol + j][vrow] = vv[j];
        }
        __syncthreads();

        // S = Q K^T  (32 q-rows x 64 k-cols per wave), split 3-MFMA
        f32x4 accs[2][4];
        size_t koff = (size_t)(b * TT + kbase + lr) * QS + D + h * HS;
#pragma unroll
        for (int nt = 0; nt < 4; ++nt) {
            size_t ko = koff + (size_t)(nt * 16) * QS;
            bf16x8 bkh0 = *(const bf16x8*)(qkvH + ko + lg * 8);
            bf16x8 bkl0 = *(const bf16x8*)(qkvL + ko + lg * 8);
            bf16x8 bkh1 = *(const bf16x8*)(qkvH + ko + 32 + lg * 8);
            bf16x8 bkl1 = *(const bf16x8*)(qkvL + ko + 32 + lg * 8);
#pragma unroll
            for (int m = 0; m < 2; ++m) {
                f32x4 s = {};
                s = __builtin_amdgcn_mfma_f32_16x16x32_bf16(aqh[m][0], bkh0, s, 0, 0, 0);
                s = __builtin_amdgcn_mfma_f32_16x16x32_bf16(aqh[m][0], bkl0, s, 0, 0, 0);
                s = __builtin_amdgcn_mfma_f32_16x16x32_bf16(aql[m][0], bkh0, s, 0, 0, 0);
                s = __builtin_amdgcn_mfma_f32_16x16x32_bf16(aqh[m][1], bkh1, s, 0, 0, 0);
                s = __builtin_amdgcn_mfma_f32_16x16x32_bf16(aqh[m][1], bkl1, s, 0, 0, 0);
                s = __builtin_amdgcn_mfma_f32_16x16x32_bf16(aql[m][1], bkh1, s, 0, 0, 0);
                accs[m][nt] = s * 8.0f;   // * sqrt(head_size), faithful to reference
            }
        }

        if (CAUSAL && kt >= 2 * qb) {
#pragma unroll
            for (int m = 0; m < 2; ++m)
#pragma unroll
                for (int nt = 0; nt < 4; ++nt)
#pragma unroll
                    for (int r = 0; r < 4; ++r) {
                        int qrow = qbase + w * 32 + m * 16 + lg * 4 + r;
                        int kcol = kbase + nt * 16 + lr;
                        if (kcol > qrow) accs[m][nt][r] = -1e30f;
                    }
        }

        // online softmax (row-wise over the 16 lanes holding this row)
#pragma unroll
        for (int m = 0; m < 2; ++m) {
            float alpha[4];
#pragma unroll
            for (int r = 0; r < 4; ++r) {
                float mx = fmaxf(fmaxf(accs[m][0][r], accs[m][1][r]),
                                 fmaxf(accs[m][2][r], accs[m][3][r]));
#pragma unroll
                for (int msk = 1; msk < 16; msk <<= 1) mx = fmaxf(mx, __shfl_xor(mx, msk, 64));
                float mnew = fmaxf(mrow[m][r], mx);
                float sum = 0.0f;
#pragma unroll
                for (int nt = 0; nt < 4; ++nt) {
                    float p = __expf(accs[m][nt][r] - mnew);
                    accs[m][nt][r] = p;
                    sum += p;
                }
#pragma unroll
                for (int msk = 1; msk < 16; msk <<= 1) sum += __shfl_xor(sum, msk, 64);
                alpha[r] = __expf(mrow[m][r] - mnew);
                lsum[m][r] = lsum[m][r] * alpha[r] + sum;
                mrow[m][r] = mnew;
            }
#pragma unroll
            for (int et = 0; et < 4; ++et)
#pragma unroll
                for (int r = 0; r < 4; ++r) acc_o[m][et][r] *= alpha[r];

            // P -> LDS (bf16 hi only; wave-private, no barrier needed)
#pragma unroll
            for (int nt = 0; nt < 4; ++nt)
#pragma unroll
                for (int r = 0; r < 4; ++r)
                    Ph[w][m * 16 + lg * 4 + r][nt * 16 + lr] = (bf16_t)accs[m][nt][r];
        }

        // O += P @ V  (pure bf16)
#pragma unroll
        for (int m = 0; m < 2; ++m) {
            bf16x8 ap0 = *(const bf16x8*)&Ph[w][m * 16 + lr][lg * 8];
            bf16x8 ap1 = *(const bf16x8*)&Ph[w][m * 16 + lr][32 + lg * 8];
#pragma unroll
            for (int et = 0; et < 4; ++et) {
                bf16x8 bv0 = *(const bf16x8*)&Vth[et * 16 + lr][lg * 8];
                bf16x8 bv1 = *(const bf16x8*)&Vth[et * 16 + lr][32 + lg * 8];
                acc_o[m][et] = __builtin_amdgcn_mfma_f32_16x16x32_bf16(ap0, bv0, acc_o[m][et], 0, 0, 0);
                acc_o[m][et] = __builtin_amdgcn_mfma_f32_16x16x32_bf16(ap1, bv1, acc_o[m][et], 0, 0, 0);
            }
        }
    }

#pragma unroll
    for (int m = 0; m < 2; ++m) {
        size_t obase = (size_t)(b * TT + qbase + w * 32 + m * 16) * D + h * HS;
#pragma unroll
        for (int r = 0; r < 4; ++r) {
            float inv = 1.0f / lsum[m][r];
#pragma unroll
            for (int et = 0; et < 4; ++et) {
                float v = acc_o[m][et][r] * inv;
                bf16_t hh = (bf16_t)v;
                size_t idx = obase + (size_t)(lg * 4 + r) * D + et * 16 + lr;
                oh[idx] = hh;
                ol[idx] = (bf16_t)(v - (float)hh);
            }
        }
    }
}

// ---------------------------------------------------------------------------
extern "C" void kernel_launch(void* const* d_in, const int* in_sizes, int n_in,
                              void* d_out, int out_size, void* d_ws, size_t ws_size,
                              hipStream_t stream)
{
    const float* x     = (const float*)d_in[0];
    const float* Wq    = (const float*)d_in[1];
    const float* bq    = (const float*)d_in[2];
    const float* Wk    = (const float*)d_in[3];
    const float* bk    = (const float*)d_in[4];
    const float* Wv    = (const float*)d_in[5];
    const float* bv    = (const float*)d_in[6];
    const float* Wp    = (const float*)d_in[7];
    const float* bp    = (const float*)d_in[8];
    const float* gamma = (const float*)d_in[9];
    const float* W1    = (const float*)d_in[10];
    const float* b1    = (const float*)d_in[11];
    const float* W2    = (const float*)d_in[12];
    const float* b2    = (const float*)d_in[13];
    float* out = (float*)d_out;

    // workspace layout (96 MB):
    //  0..16  : nrm hi/lo (8 MB each); also ao hi/lo (aliased, nrm dead by attn)
    // 16..64  : fused qkv hi (24 MB) + lo (24 MB); h1 hi/lo (32+32) alias 16..80
    // 64..80  : spare (h1 lo tail); bias3072 lives at 64 MB while qkv in flight
    // 80..96  : weight slot (attn: wqkv 12 + wp 4; ffn: W1 16 then W2 16)
    char* base = (char*)d_ws;
    bf16_t* nrmH  = (bf16_t*)(base);
    bf16_t* nrmL  = (bf16_t*)(base + (8u  << 20));
    bf16_t* qkvH  = (bf16_t*)(base + (16u << 20));
    bf16_t* qkvL  = (bf16_t*)(base + (40u << 20));
    float*  bias3 = (float*)(base + (64u << 20));
    bf16_t* h1H   = (bf16_t*)(base + (16u << 20));   // 32 MB
    bf16_t* h1L   = (bf16_t*)(base + (48u << 20));   // 32 MB
    bf16_t* wsl   = (bf16_t*)(base + (80u << 20));   // 16 MB weight slot
    bf16_t* aoH = nrmH, *aoL = nrmL;
    float* abuf = out;   // 'a' lives in d_out, dead before final write
    float* bbuf = out;   // 'b' overwrites 'a' in d_out (a unused after rmsnorm)

    // attention-phase weight slot: wqkv hi [3072][1024], wqkv lo, wp hi, wp lo
    size_t DD = (size_t)D * D;
    bf16_t* wqkvH = wsl;
    bf16_t* wqkvL = wsl + 3 * DD;
    bf16_t* wpH   = wsl + 6 * DD;
    bf16_t* wpL   = wsl + 7 * DD;

    dim3 blk(256);
    dim3 gcvD(D / 64, D / 64);
    dim3 gcv1(D / 64, HF / 64);
    dim3 gcv2(HF / 64, D / 64);
    dim3 gQKV(3 * D / 128, MR / 128);   // 24 x 32 = 768 blocks, TN=128
    dim3 gP(D / 64, MR / 128);          // 16 x 32 = 512 blocks, TN=64
    dim3 gF(HF / 128, MR / 128);        // 32 x 32 = 1024 blocks, TN=128
    dim3 gA(TT / 128, NH, BB);          // 8 x 16 x 4 = 512 blocks

    // ---- a = x + attn(rmsnorm(x), causal=false)
    rmsnorm_kernel<<<MR, blk, 0, stream>>>(x, gamma, nrmH, nrmL);
    concat_bias_kernel<<<12, blk, 0, stream>>>(bq, bk, bv, bias3);
    convw_kernel<<<gcvD, blk, 0, stream>>>(Wq, wqkvH,          wqkvL,          D, D);
    convw_kernel<<<gcvD, blk, 0, stream>>>(Wk, wqkvH + DD,     wqkvL + DD,     D, D);
    convw_kernel<<<gcvD, blk, 0, stream>>>(Wv, wqkvH + 2 * DD, wqkvL + 2 * DD, D, D);
    convw_kernel<<<gcvD, blk, 0, stream>>>(Wp, wpH,            wpL,            D, D);
    gemm_kernel<128, 1, false, false><<<gQKV, blk, 0, stream>>>(nrmH, nrmL, wqkvH, wqkvL, bias3, nullptr, nullptr, qkvH, qkvL, 3 * D, D);
    attn_kernel<false><<<gA, blk, 0, stream>>>(qkvH, qkvL, aoH, aoL);
    gemm_kernel<64, 0, false, true><<<gP, blk, 0, stream>>>(aoH, aoL, wpH, wpL, bp, x, abuf, nullptr, nullptr, D, D);

    // ---- b = x + ffwd(rmsnorm(a))
    rmsnorm_kernel<<<MR, blk, 0, stream>>>(abuf, gamma, nrmH, nrmL);
    convw_kernel<<<gcv1, blk, 0, stream>>>(W1, wsl, wsl + (size_t)HF * D, D, HF);
    gemm_kernel<128, 1, true, false><<<gF, blk, 0, stream>>>(nrmH, nrmL, wsl, wsl + (size_t)HF * D, b1, nullptr, nullptr, h1H, h1L, HF, D);
    convw_kernel<<<gcv2, blk, 0, stream>>>(W2, wsl, wsl + (size_t)D * HF, HF, D);
    gemm_kernel<64, 0, false, true><<<gP, blk, 0, stream>>>(h1H, h1L, wsl, wsl + (size_t)D * HF, b2, x, bbuf, nullptr, nullptr, D, HF);

    // ---- c = b + attn(rmsnorm(b), causal=true)
    rmsnorm_kernel<<<MR, blk, 0, stream>>>(bbuf, gamma, nrmH, nrmL);
    concat_bias_kernel<<<12, blk, 0, stream>>>(bq, bk, bv, bias3);
    convw_kernel<<<gcvD, blk, 0, stream>>>(Wq, wqkvH,          wqkvL,          D, D);
    convw_kernel<<<gcvD, blk, 0, stream>>>(Wk, wqkvH + DD,     wqkvL + DD,     D, D);
    convw_kernel<<<gcvD, blk, 0, stream>>>(Wv, wqkvH + 2 * DD, wqkvL + 2 * DD, D, D);
    convw_kernel<<<gcvD, blk, 0, stream>>>(Wp, wpH,            wpL,            D, D);
    gemm_kernel<128, 1, false, false><<<gQKV, blk, 0, stream>>>(nrmH, nrmL, wqkvH, wqkvL, bias3, nullptr, nullptr, qkvH, qkvL, 3 * D, D);
    attn_kernel<true><<<gA, blk, 0, stream>>>(qkvH, qkvL, aoH, aoL);
    gemm_kernel<64, 0, false, true><<<gP, blk, 0, stream>>>(aoH, aoL, wpH, wpL, bp, bbuf, out, nullptr, nullptr, D, D);
}

// Round 7
// 674.158 us; speedup vs baseline: 2.5590x; 1.0779x over previous
//
#include <hip/hip_runtime.h>
#include <cstdint>
#include <cstddef>

typedef __bf16 bf16_t;
typedef __attribute__((ext_vector_type(8))) __bf16 bf16x8;
typedef __attribute__((ext_vector_type(4))) __bf16 bf16x4;
typedef __attribute__((ext_vector_type(4))) float f32x4;

constexpr int D  = 1024;   // d_model
constexpr int TT = 1024;   // seq len
constexpr int BB = 4;      // batch
constexpr int NH = 16;     // heads
constexpr int HS = 64;     // head size
constexpr int MR = BB * TT; // 4096 rows
constexpr int HF = 4096;   // ffn hidden

__device__ inline void gload_lds16(const bf16_t* g, bf16_t* l)
{
    __builtin_amdgcn_global_load_lds(
        (const __attribute__((address_space(1))) void*)g,
        (__attribute__((address_space(3))) void*)l, 16, 0, 0);
}

// ---------------------------------------------------------------------------
// RMSNorm: f32 in -> bf16 hi/lo planes out. One block (256 thr) per row.
// ---------------------------------------------------------------------------
__global__ __launch_bounds__(256) void rmsnorm_kernel(const float* __restrict__ x,
                                                      const float* __restrict__ gamma,
                                                      bf16_t* __restrict__ oh,
                                                      bf16_t* __restrict__ ol)
{
    int row = blockIdx.x;
    int t   = threadIdx.x;
    const float* xr = x + (size_t)row * D;
    float4 xv = *(const float4*)(xr + t * 4);
    float ss = xv.x * xv.x + xv.y * xv.y + xv.z * xv.z + xv.w * xv.w;
#pragma unroll
    for (int m = 1; m < 64; m <<= 1) ss += __shfl_xor(ss, m, 64);
    __shared__ float part[4];
    if ((t & 63) == 0) part[t >> 6] = ss;
    __syncthreads();
    float tot   = part[0] + part[1] + part[2] + part[3];
    float scale = rsqrtf(tot * (1.0f / D) + 1e-6f);
    float4 gv = *(const float4*)(gamma + t * 4);
    float vals[4] = {xv.x * scale * gv.x, xv.y * scale * gv.y,
                     xv.z * scale * gv.z, xv.w * scale * gv.w};
    bf16x4 vh, vl;
#pragma unroll
    for (int j = 0; j < 4; ++j) {
        bf16_t h = (bf16_t)vals[j];
        vh[j] = h;
        vl[j] = (bf16_t)(vals[j] - (float)h);
    }
    *(bf16x4*)(oh + (size_t)row * D + t * 4) = vh;
    *(bf16x4*)(ol + (size_t)row * D + t * 4) = vl;
}

// ---------------------------------------------------------------------------
// concat 3x [1024] f32 biases into one [3072] buffer
// ---------------------------------------------------------------------------
__global__ __launch_bounds__(256) void concat_bias_kernel(const float* __restrict__ a,
                                                          const float* __restrict__ b,
                                                          const float* __restrict__ c,
                                                          float* __restrict__ o)
{
    int i = blockIdx.x * 256 + threadIdx.x;
    o[i] = i < 1024 ? a[i] : (i < 2048 ? b[i - 1024] : c[i - 2048]);
}

// ---------------------------------------------------------------------------
// Weight convert: W f32 [K][N] -> dH/dL bf16 [N][K] planes (transposed).
// 64x64 tile via padded LDS transpose. Grid (K/64, N/64), 256 thr.
// ---------------------------------------------------------------------------
__global__ __launch_bounds__(256) void convw_kernel(const float* __restrict__ W,
                                                    bf16_t* __restrict__ dH,
                                                    bf16_t* __restrict__ dL,
                                                    int K, int N)
{
    __shared__ float sld[64][65];
    int t = threadIdx.x;
    int k0 = blockIdx.x * 64, n0 = blockIdx.y * 64;
    int kr = t >> 4, nc = (t & 15) * 4;
#pragma unroll
    for (int p = 0; p < 4; ++p) {
        int k = p * 16 + kr;
        float4 v = *(const float4*)(W + (size_t)(k0 + k) * N + n0 + nc);
        sld[k][nc] = v.x; sld[k][nc + 1] = v.y; sld[k][nc + 2] = v.z; sld[k][nc + 3] = v.w;
    }
    __syncthreads();
    int n = t >> 2, kh = (t & 3) * 16;
    bf16x8 h0, l0, h1, l1;
#pragma unroll
    for (int j = 0; j < 8; ++j) {
        float v = sld[kh + j][n];
        bf16_t h = (bf16_t)v;
        h0[j] = h; l0[j] = (bf16_t)(v - (float)h);
    }
#pragma unroll
    for (int j = 0; j < 8; ++j) {
        float v = sld[kh + 8 + j][n];
        bf16_t h = (bf16_t)v;
        h1[j] = h; l1[j] = (bf16_t)(v - (float)h);
    }
    size_t o = (size_t)(n0 + n) * K + k0 + kh;
    *(bf16x8*)(dH + o)     = h0;
    *(bf16x8*)(dH + o + 8) = h1;
    *(bf16x8*)(dL + o)     = l0;
    *(bf16x8*)(dL + o + 8) = l1;
}

// ---------------------------------------------------------------------------
// Split-precision GEMM, 128xTN tile (TN = 64 or 128), BK=32, 4 waves.
// A bf16 [M][K] hi (+ optional lo plane if ALO); W hi/lo bf16 [N][K].
// ALO=1: 3 MFMAs per pair (hh+hl+lh).  ALO=0: 2 MFMAs (hh+hl).
// global_load_lds(16B) staging into linear LDS, XOR-swizzled source+read.
// OUTM: 0 = f32 out, 1 = bf16 hi/lo planes, 2 = bf16 hi only.
// ---------------------------------------------------------------------------
template<int TN, bool ALO, int OUTM, bool RELU, bool RESID>
__global__ __launch_bounds__(256, 2) void gemm_kernel(
    const bf16_t* __restrict__ Ahp, const bf16_t* __restrict__ Alp,
    const bf16_t* __restrict__ Whp, const bf16_t* __restrict__ Wlp,
    const float* __restrict__ bias, const float* resid,
    float* outf, bf16_t* __restrict__ outh, bf16_t* __restrict__ outl,
    int N, int K)
{
    constexpr int NF = TN / 32;          // n-frags per wave
    constexpr int AP = ALO ? 2 : 1;      // A planes
    __shared__ bf16_t sA[AP][128][32];   // [plane][m][k], linear (gload_lds dest)
    __shared__ bf16_t sW[2][TN][32];     // [hi/lo][n][k]

    int t = threadIdx.x;
    int l = t & 63, w = t >> 6;
    int lr = l & 15, lg = l >> 4;

    // XCD-aware block swizzle (all grids have nwg % 8 == 0)
    int gx  = gridDim.x;
    int nwg = gx * gridDim.y;
    int bid = blockIdx.y * gx + blockIdx.x;
    int s   = (bid & 7) * (nwg >> 3) + (bid >> 3);
    int nb  = s % gx, mb = s / gx;
    int m0 = mb * 128, n0 = nb * TN;
    int wr = (w >> 1) * 64, wc = (w & 1) * (TN / 2);

    f32x4 acc[4][NF] = {};

    int srow = (l >> 2);      // 0..15 within chunk
    int sch  = l & 3;         // 16B slot within 64B row

    for (int kk = 0; kk < K; kk += 32) {
        __syncthreads();
        // A planes: 128 rows = 4 waves x 2 chunks x 16
#pragma unroll
        for (int c = 0; c < 2; ++c) {
            int rbase = w * 32 + c * 16;
            int row = rbase + srow;
            int f = (row >> 1) & 3;
            size_t goff = (size_t)row * K + kk + (size_t)((sch ^ f)) * 8;
            gload_lds16(Ahp + (size_t)m0 * K + goff, &sA[0][rbase][0]);
            if (ALO) gload_lds16(Alp + (size_t)m0 * K + goff, &sA[AP - 1][rbase][0]);
        }
        // W planes: TN rows = 4 waves x (TN/64) chunks x 16
#pragma unroll
        for (int c = 0; c < TN / 64; ++c) {
            int rbase = w * (TN / 4) + c * 16;
            int row = rbase + srow;
            int f = (row >> 1) & 3;
            size_t goff = (size_t)row * K + kk + (size_t)((sch ^ f)) * 8;
            gload_lds16(Whp + (size_t)n0 * K + goff, &sW[0][rbase][0]);
            gload_lds16(Wlp + (size_t)n0 * K + goff, &sW[1][rbase][0]);
        }
        __syncthreads();

        bf16x8 a0[4], a1[4], b0[NF], b1[NF];
#pragma unroll
        for (int m = 0; m < 4; ++m) {
            int row = wr + m * 16 + lr;
            int sl = lg ^ ((row >> 1) & 3);
            a0[m] = *(const bf16x8*)&sA[0][row][sl * 8];
            if (ALO) a1[m] = *(const bf16x8*)&sA[AP - 1][row][sl * 8];
        }
#pragma unroll
        for (int n = 0; n < NF; ++n) {
            int row = wc + n * 16 + lr;
            int sl = lg ^ ((row >> 1) & 3);
            b0[n] = *(const bf16x8*)&sW[0][row][sl * 8];
            b1[n] = *(const bf16x8*)&sW[1][row][sl * 8];
        }
        // hh pass, then hl, then (if ALO) lh
#pragma unroll
        for (int m = 0; m < 4; ++m)
#pragma unroll
            for (int n = 0; n < NF; ++n)
                acc[m][n] = __builtin_amdgcn_mfma_f32_16x16x32_bf16(a0[m], b0[n], acc[m][n], 0, 0, 0);
#pragma unroll
        for (int m = 0; m < 4; ++m)
#pragma unroll
            for (int n = 0; n < NF; ++n)
                acc[m][n] = __builtin_amdgcn_mfma_f32_16x16x32_bf16(a0[m], b1[n], acc[m][n], 0, 0, 0);
        if (ALO) {
#pragma unroll
            for (int m = 0; m < 4; ++m)
#pragma unroll
                for (int n = 0; n < NF; ++n)
                    acc[m][n] = __builtin_amdgcn_mfma_f32_16x16x32_bf16(a1[m], b0[n], acc[m][n], 0, 0, 0);
        }
    }

#pragma unroll
    for (int m = 0; m < 4; ++m) {
#pragma unroll
        for (int n = 0; n < NF; ++n) {
            int col = n0 + wc + n * 16 + lr;
            float bv = bias[col];
#pragma unroll
            for (int r = 0; r < 4; ++r) {
                int row = m0 + wr + m * 16 + lg * 4 + r;
                float v = acc[m][n][r] + bv;
                if (RELU)  v = (v >= 0.0f) ? v : 0.1f * v;
                if (RESID) v += resid[(size_t)row * N + col];
                if (OUTM == 0) {
                    outf[(size_t)row * N + col] = v;
                } else if (OUTM == 2) {
                    outh[(size_t)row * N + col] = (bf16_t)v;
                } else {
                    bf16_t h = (bf16_t)v;
                    outh[(size_t)row * N + col] = h;
                    outl[(size_t)row * N + col] = (bf16_t)(v - (float)h);
                }
            }
        }
    }
}

// ---------------------------------------------------------------------------
// Flash attention from fused QKV planes (row stride 3D; q/k/v at col 0/D/2D).
// Block = 256 thr (4 waves), 128 q-rows per block (32/wave).
// QK^T split-precision (3 MFMA/pair); PV pure bf16-hi. V staged hi-only.
// ---------------------------------------------------------------------------
template<bool CAUSAL>
__global__ __launch_bounds__(256, 2) void attn_kernel(
    const bf16_t* __restrict__ qkvH, const bf16_t* __restrict__ qkvL,
    bf16_t* __restrict__ oh, bf16_t* __restrict__ ol)
{
    __shared__ bf16_t Vth[64][70];     // [e][kk] hi, pad 70 (~2-way banks)
    __shared__ bf16_t Ph[4][32][70];   // per-wave [qrow][kk] hi

    int tid = threadIdx.x;
    int qb = blockIdx.x, h = blockIdx.y, b = blockIdx.z;
    int l = tid & 63, w = tid >> 6;
    int lr = l & 15, lg = l >> 4;
    int qbase = qb * 128;
    const int QS = 3 * D;

    // Q frags: 32 rows per wave (2 x 16-row frags), hi/lo, both k-halves
    bf16x8 aqh[2][2], aql[2][2];
#pragma unroll
    for (int m = 0; m < 2; ++m) {
        size_t qoff = (size_t)(b * TT + qbase + w * 32 + m * 16 + lr) * QS + h * HS;
#pragma unroll
        for (int c = 0; c < 2; ++c) {
            aqh[m][c] = *(const bf16x8*)(qkvH + qoff + c * 32 + lg * 8);
            aql[m][c] = *(const bf16x8*)(qkvL + qoff + c * 32 + lg * 8);
        }
    }

    float mrow[2][4], lsum[2][4];
    f32x4 acc_o[2][4] = {};
#pragma unroll
    for (int m = 0; m < 2; ++m)
#pragma unroll
        for (int r = 0; r < 4; ++r) { mrow[m][r] = -1e30f; lsum[m][r] = 0.0f; }

    int ktmax = CAUSAL ? (2 * qb + 1) : (TT / 64 - 1);
    for (int kt = 0; kt <= ktmax; ++kt) {
        int kbase = kt * 64;
        __syncthreads();
        // stage V tile (hi only) transposed: Vth[e][kk]
#pragma unroll
        for (int rr = 0; rr < 2; ++rr) {
            int vrow = (tid >> 3) + rr * 32;
            int vcol = (tid & 7) * 8;
            size_t voff = (size_t)(b * TT + kbase + vrow) * QS + 2 * D + h * HS + vcol;
            bf16x8 vv = *(const bf16x8*)(qkvH + voff);
#pragma unroll
            for (int j = 0; j < 8; ++j) Vth[vcol + j][vrow] = vv[j];
        }
        __syncthreads();

        // S = Q K^T  (32 q-rows x 64 k-cols per wave), split 3-MFMA
        f32x4 accs[2][4];
        size_t koff = (size_t)(b * TT + kbase + lr) * QS + D + h * HS;
#pragma unroll
        for (int nt = 0; nt < 4; ++nt) {
            size_t ko = koff + (size_t)(nt * 16) * QS;
            bf16x8 bkh0 = *(const bf16x8*)(qkvH + ko + lg * 8);
            bf16x8 bkl0 = *(const bf16x8*)(qkvL + ko + lg * 8);
            bf16x8 bkh1 = *(const bf16x8*)(qkvH + ko + 32 + lg * 8);
            bf16x8 bkl1 = *(const bf16x8*)(qkvL + ko + 32 + lg * 8);
#pragma unroll
            for (int m = 0; m < 2; ++m) {
                f32x4 s = {};
                s = __builtin_amdgcn_mfma_f32_16x16x32_bf16(aqh[m][0], bkh0, s, 0, 0, 0);
                s = __builtin_amdgcn_mfma_f32_16x16x32_bf16(aqh[m][0], bkl0, s, 0, 0, 0);
                s = __builtin_amdgcn_mfma_f32_16x16x32_bf16(aql[m][0], bkh0, s, 0, 0, 0);
                s = __builtin_amdgcn_mfma_f32_16x16x32_bf16(aqh[m][1], bkh1, s, 0, 0, 0);
                s = __builtin_amdgcn_mfma_f32_16x16x32_bf16(aqh[m][1], bkl1, s, 0, 0, 0);
                s = __builtin_amdgcn_mfma_f32_16x16x32_bf16(aql[m][1], bkh1, s, 0, 0, 0);
                accs[m][nt] = s * 8.0f;   // * sqrt(head_size), faithful to reference
            }
        }

        if (CAUSAL && kt >= 2 * qb) {
#pragma unroll
            for (int m = 0; m < 2; ++m)
#pragma unroll
                for (int nt = 0; nt < 4; ++nt)
#pragma unroll
                    for (int r = 0; r < 4; ++r) {
                        int qrow = qbase + w * 32 + m * 16 + lg * 4 + r;
                        int kcol = kbase + nt * 16 + lr;
                        if (kcol > qrow) accs[m][nt][r] = -1e30f;
                    }
        }

        // online softmax (row-wise over the 16 lanes holding this row)
#pragma unroll
        for (int m = 0; m < 2; ++m) {
            float alpha[4];
#pragma unroll
            for (int r = 0; r < 4; ++r) {
                float mx = fmaxf(fmaxf(accs[m][0][r], accs[m][1][r]),
                                 fmaxf(accs[m][2][r], accs[m][3][r]));
#pragma unroll
                for (int msk = 1; msk < 16; msk <<= 1) mx = fmaxf(mx, __shfl_xor(mx, msk, 64));
                float mnew = fmaxf(mrow[m][r], mx);
                float sum = 0.0f;
#pragma unroll
                for (int nt = 0; nt < 4; ++nt) {
                    float p = __expf(accs[m][nt][r] - mnew);
                    accs[m][nt][r] = p;
                    sum += p;
                }
#pragma unroll
                for (int msk = 1; msk < 16; msk <<= 1) sum += __shfl_xor(sum, msk, 64);
                alpha[r] = __expf(mrow[m][r] - mnew);
                lsum[m][r] = lsum[m][r] * alpha[r] + sum;
                mrow[m][r] = mnew;
            }
#pragma unroll
            for (int et = 0; et < 4; ++et)
#pragma unroll
                for (int r = 0; r < 4; ++r) acc_o[m][et][r] *= alpha[r];

            // P -> LDS (bf16 hi only; wave-private, no barrier needed)
#pragma unroll
            for (int nt = 0; nt < 4; ++nt)
#pragma unroll
                for (int r = 0; r < 4; ++r)
                    Ph[w][m * 16 + lg * 4 + r][nt * 16 + lr] = (bf16_t)accs[m][nt][r];
        }

        // O += P @ V  (pure bf16)
#pragma unroll
        for (int m = 0; m < 2; ++m) {
            bf16x8 ap0 = *(const bf16x8*)&Ph[w][m * 16 + lr][lg * 8];
            bf16x8 ap1 = *(const bf16x8*)&Ph[w][m * 16 + lr][32 + lg * 8];
#pragma unroll
            for (int et = 0; et < 4; ++et) {
                bf16x8 bv0 = *(const bf16x8*)&Vth[et * 16 + lr][lg * 8];
                bf16x8 bv1 = *(const bf16x8*)&Vth[et * 16 + lr][32 + lg * 8];
                acc_o[m][et] = __builtin_amdgcn_mfma_f32_16x16x32_bf16(ap0, bv0, acc_o[m][et], 0, 0, 0);
                acc_o[m][et] = __builtin_amdgcn_mfma_f32_16x16x32_bf16(ap1, bv1, acc_o[m][et], 0, 0, 0);
            }
        }
    }

#pragma unroll
    for (int m = 0; m < 2; ++m) {
        size_t obase = (size_t)(b * TT + qbase + w * 32 + m * 16) * D + h * HS;
#pragma unroll
        for (int r = 0; r < 4; ++r) {
            float inv = 1.0f / lsum[m][r];
#pragma unroll
            for (int et = 0; et < 4; ++et) {
                float v = acc_o[m][et][r] * inv;
                bf16_t hh = (bf16_t)v;
                size_t idx = obase + (size_t)(lg * 4 + r) * D + et * 16 + lr;
                oh[idx] = hh;
                ol[idx] = (bf16_t)(v - (float)hh);
            }
        }
    }
}

// ---------------------------------------------------------------------------
extern "C" void kernel_launch(void* const* d_in, const int* in_sizes, int n_in,
                              void* d_out, int out_size, void* d_ws, size_t ws_size,
                              hipStream_t stream)
{
    const float* x     = (const float*)d_in[0];
    const float* Wq    = (const float*)d_in[1];
    const float* bq    = (const float*)d_in[2];
    const float* Wk    = (const float*)d_in[3];
    const float* bk    = (const float*)d_in[4];
    const float* Wv    = (const float*)d_in[5];
    const float* bv    = (const float*)d_in[6];
    const float* Wp    = (const float*)d_in[7];
    const float* bp    = (const float*)d_in[8];
    const float* gamma = (const float*)d_in[9];
    const float* W1    = (const float*)d_in[10];
    const float* b1    = (const float*)d_in[11];
    const float* W2    = (const float*)d_in[12];
    const float* b2    = (const float*)d_in[13];
    float* out = (float*)d_out;

    // workspace layout (96 MB):
    //  0..16  : nrm hi/lo (8 MB each); also ao hi/lo (aliased)
    // 16..64  : qkv hi (24) + qkv lo (24); h1 bf16-hi (32) aliases 16..48
    // 48..64  : W1 conv slot (16 MB, ffn phase; aliases qkv lo tail)
    // 64..80  : bias3072 (attn phases) / W2 conv slot (ffn phase)
    // 80..96  : persistent attn weights: wqkv hi 6, wqkv lo 6, wp hi 2, wp lo 2
    char* base = (char*)d_ws;
    bf16_t* nrmH  = (bf16_t*)(base);
    bf16_t* nrmL  = (bf16_t*)(base + (8u  << 20));
    bf16_t* qkvH  = (bf16_t*)(base + (16u << 20));
    bf16_t* qkvL  = (bf16_t*)(base + (40u << 20));
    bf16_t* h1H   = (bf16_t*)(base + (16u << 20));   // 32 MB, hi only
    bf16_t* w1sl  = (bf16_t*)(base + (48u << 20));   // 16 MB
    float*  bias3 = (float*)(base + (64u << 20));
    bf16_t* w2sl  = (bf16_t*)(base + (64u << 20));   // 16 MB
    bf16_t* wsl   = (bf16_t*)(base + (80u << 20));   // 16 MB persistent
    bf16_t* aoH = nrmH, *aoL = nrmL;
    float* abuf = out;   // 'a' lives in d_out, dead before final write
    float* bbuf = out;   // 'b' overwrites 'a' in d_out (a unused after rmsnorm)

    // persistent attn weights: wqkv hi [3072][1024], wqkv lo, wp hi, wp lo
    size_t DD = (size_t)D * D;
    bf16_t* wqkvH = wsl;
    bf16_t* wqkvL = wsl + 3 * DD;
    bf16_t* wpH   = wsl + 6 * DD;
    bf16_t* wpL   = wsl + 7 * DD;

    dim3 blk(256);
    dim3 gcvD(D / 64, D / 64);
    dim3 gcv1(D / 64, HF / 64);
    dim3 gcv2(HF / 64, D / 64);
    dim3 gQKV(3 * D / 128, MR / 128);   // 24 x 32 = 768 blocks, TN=128
    dim3 gP(D / 64, MR / 128);          // 16 x 32 = 512 blocks, TN=64
    dim3 gF(HF / 128, MR / 128);        // 32 x 32 = 1024 blocks, TN=128
    dim3 gA(TT / 128, NH, BB);          // 8 x 16 x 4 = 512 blocks

    // ---- a = x + attn(rmsnorm(x), causal=false)
    rmsnorm_kernel<<<MR, blk, 0, stream>>>(x, gamma, nrmH, nrmL);
    concat_bias_kernel<<<12, blk, 0, stream>>>(bq, bk, bv, bias3);
    convw_kernel<<<gcvD, blk, 0, stream>>>(Wq, wqkvH,          wqkvL,          D, D);
    convw_kernel<<<gcvD, blk, 0, stream>>>(Wk, wqkvH + DD,     wqkvL + DD,     D, D);
    convw_kernel<<<gcvD, blk, 0, stream>>>(Wv, wqkvH + 2 * DD, wqkvL + 2 * DD, D, D);
    convw_kernel<<<gcvD, blk, 0, stream>>>(Wp, wpH,            wpL,            D, D);
    gemm_kernel<128, true, 1, false, false><<<gQKV, blk, 0, stream>>>(nrmH, nrmL, wqkvH, wqkvL, bias3, nullptr, nullptr, qkvH, qkvL, 3 * D, D);
    attn_kernel<false><<<gA, blk, 0, stream>>>(qkvH, qkvL, aoH, aoL);
    gemm_kernel<64, true, 0, false, true><<<gP, blk, 0, stream>>>(aoH, aoL, wpH, wpL, bp, x, abuf, nullptr, nullptr, D, D);

    // ---- b = x + ffwd(rmsnorm(a))
    rmsnorm_kernel<<<MR, blk, 0, stream>>>(abuf, gamma, nrmH, nrmL);
    convw_kernel<<<gcv1, blk, 0, stream>>>(W1, w1sl, w1sl + (size_t)HF * D, D, HF);
    gemm_kernel<128, true, 2, true, false><<<gF, blk, 0, stream>>>(nrmH, nrmL, w1sl, w1sl + (size_t)HF * D, b1, nullptr, nullptr, h1H, nullptr, HF, D);
    convw_kernel<<<gcv2, blk, 0, stream>>>(W2, w2sl, w2sl + (size_t)D * HF, HF, D);
    gemm_kernel<64, false, 0, false, true><<<gP, blk, 0, stream>>>(h1H, nullptr, w2sl, w2sl + (size_t)D * HF, b2, x, bbuf, nullptr, nullptr, D, HF);

    // ---- c = b + attn(rmsnorm(b), causal=true)  (attn weights still resident)
    rmsnorm_kernel<<<MR, blk, 0, stream>>>(bbuf, gamma, nrmH, nrmL);
    concat_bias_kernel<<<12, blk, 0, stream>>>(bq, bk, bv, bias3);
    gemm_kernel<128, true, 1, false, false><<<gQKV, blk, 0, stream>>>(nrmH, nrmL, wqkvH, wqkvL, bias3, nullptr, nullptr, qkvH, qkvL, 3 * D, D);
    attn_kernel<true><<<gA, blk, 0, stream>>>(qkvH, qkvL, aoH, aoL);
    gemm_kernel<64, true, 0, false, true><<<gP, blk, 0, stream>>>(aoH, aoL, wpH, wpL, bp, bbuf, out, nullptr, nullptr, D, D);
}

// Round 8
// 620.636 us; speedup vs baseline: 2.7797x; 1.0862x over previous
//
#include <hip/hip_runtime.h>
#include <cstdint>
#include <cstddef>

typedef __bf16 bf16_t;
typedef __attribute__((ext_vector_type(8))) __bf16 bf16x8;
typedef __attribute__((ext_vector_type(4))) __bf16 bf16x4;
typedef __attribute__((ext_vector_type(4))) float f32x4;

constexpr int D  = 1024;   // d_model
constexpr int TT = 1024;   // seq len
constexpr int BB = 4;      // batch
constexpr int NH = 16;     // heads
constexpr int HS = 64;     // head size
constexpr int MR = BB * TT; // 4096 rows
constexpr int HF = 4096;   // ffn hidden

__device__ inline void gload_lds16(const bf16_t* g, bf16_t* l)
{
    __builtin_amdgcn_global_load_lds(
        (const __attribute__((address_space(1))) void*)g,
        (__attribute__((address_space(3))) void*)l, 16, 0, 0);
}

// ---------------------------------------------------------------------------
// RMSNorm: f32 in -> bf16 hi (+ optional lo) planes. One block per row.
// ---------------------------------------------------------------------------
template<bool LO>
__global__ __launch_bounds__(256) void rmsnorm_kernel(const float* __restrict__ x,
                                                      const float* __restrict__ gamma,
                                                      bf16_t* __restrict__ oh,
                                                      bf16_t* __restrict__ ol)
{
    int row = blockIdx.x;
    int t   = threadIdx.x;
    const float* xr = x + (size_t)row * D;
    float4 xv = *(const float4*)(xr + t * 4);
    float ss = xv.x * xv.x + xv.y * xv.y + xv.z * xv.z + xv.w * xv.w;
#pragma unroll
    for (int m = 1; m < 64; m <<= 1) ss += __shfl_xor(ss, m, 64);
    __shared__ float part[4];
    if ((t & 63) == 0) part[t >> 6] = ss;
    __syncthreads();
    float tot   = part[0] + part[1] + part[2] + part[3];
    float scale = rsqrtf(tot * (1.0f / D) + 1e-6f);
    float4 gv = *(const float4*)(gamma + t * 4);
    float vals[4] = {xv.x * scale * gv.x, xv.y * scale * gv.y,
                     xv.z * scale * gv.z, xv.w * scale * gv.w};
    bf16x4 vh, vl;
#pragma unroll
    for (int j = 0; j < 4; ++j) {
        bf16_t h = (bf16_t)vals[j];
        vh[j] = h;
        vl[j] = (bf16_t)(vals[j] - (float)h);
    }
    *(bf16x4*)(oh + (size_t)row * D + t * 4) = vh;
    if (LO) *(bf16x4*)(ol + (size_t)row * D + t * 4) = vl;
}

// ---------------------------------------------------------------------------
// concat 3x [1024] f32 biases into one [3072] buffer
// ---------------------------------------------------------------------------
__global__ __launch_bounds__(256) void concat_bias_kernel(const float* __restrict__ a,
                                                          const float* __restrict__ b,
                                                          const float* __restrict__ c,
                                                          float* __restrict__ o)
{
    int i = blockIdx.x * 256 + threadIdx.x;
    o[i] = i < 1024 ? a[i] : (i < 2048 ? b[i - 1024] : c[i - 2048]);
}

// ---------------------------------------------------------------------------
// Weight convert: W f32 [K][N] -> dH (+ optional dL) bf16 [N][K] (transposed).
// 64x64 tile via padded LDS transpose. Grid (K/64, N/64), 256 thr.
// ---------------------------------------------------------------------------
template<bool LO>
__global__ __launch_bounds__(256) void convw_kernel(const float* __restrict__ W,
                                                    bf16_t* __restrict__ dH,
                                                    bf16_t* __restrict__ dL,
                                                    int K, int N)
{
    __shared__ float sld[64][65];
    int t = threadIdx.x;
    int k0 = blockIdx.x * 64, n0 = blockIdx.y * 64;
    int kr = t >> 4, nc = (t & 15) * 4;
#pragma unroll
    for (int p = 0; p < 4; ++p) {
        int k = p * 16 + kr;
        float4 v = *(const float4*)(W + (size_t)(k0 + k) * N + n0 + nc);
        sld[k][nc] = v.x; sld[k][nc + 1] = v.y; sld[k][nc + 2] = v.z; sld[k][nc + 3] = v.w;
    }
    __syncthreads();
    int n = t >> 2, kh = (t & 3) * 16;
    bf16x8 h0, l0, h1, l1;
#pragma unroll
    for (int j = 0; j < 8; ++j) {
        float v = sld[kh + j][n];
        bf16_t h = (bf16_t)v;
        h0[j] = h; l0[j] = (bf16_t)(v - (float)h);
    }
#pragma unroll
    for (int j = 0; j < 8; ++j) {
        float v = sld[kh + 8 + j][n];
        bf16_t h = (bf16_t)v;
        h1[j] = h; l1[j] = (bf16_t)(v - (float)h);
    }
    size_t o = (size_t)(n0 + n) * K + k0 + kh;
    *(bf16x8*)(dH + o)     = h0;
    *(bf16x8*)(dH + o + 8) = h1;
    if (LO) {
        *(bf16x8*)(dL + o)     = l0;
        *(bf16x8*)(dL + o + 8) = l1;
    }
}

// ---------------------------------------------------------------------------
// Split-precision GEMM, 128xTN tile (TN = 64 or 128), BK=32, 4 waves.
// A bf16 [M][K] hi (+ lo if ALO); W bf16 [N][K] hi (+ lo if WLO).
// MFMA passes: hh, + hl (if WLO), + lh (if ALO).
// global_load_lds(16B) staging into linear LDS, XOR-swizzled source+read.
// OUTM: 0 = f32 out, 1 = bf16 hi/lo planes, 2 = bf16 hi only.
// ---------------------------------------------------------------------------
template<int TN, bool ALO, bool WLO, int OUTM, bool RELU, bool RESID>
__global__ __launch_bounds__(256, 2) void gemm_kernel(
    const bf16_t* __restrict__ Ahp, const bf16_t* __restrict__ Alp,
    const bf16_t* __restrict__ Whp, const bf16_t* __restrict__ Wlp,
    const float* __restrict__ bias, const float* resid,
    float* outf, bf16_t* __restrict__ outh, bf16_t* __restrict__ outl,
    int N, int K)
{
    constexpr int NF = TN / 32;          // n-frags per wave
    constexpr int AP = ALO ? 2 : 1;      // A planes
    constexpr int WP = WLO ? 2 : 1;      // W planes
    __shared__ bf16_t sA[AP][128][32];   // [plane][m][k], linear (gload_lds dest)
    __shared__ bf16_t sW[WP][TN][32];    // [plane][n][k]

    int t = threadIdx.x;
    int l = t & 63, w = t >> 6;
    int lr = l & 15, lg = l >> 4;

    // XCD-aware block swizzle (all grids have nwg % 8 == 0)
    int gx  = gridDim.x;
    int nwg = gx * gridDim.y;
    int bid = blockIdx.y * gx + blockIdx.x;
    int s   = (bid & 7) * (nwg >> 3) + (bid >> 3);
    int nb  = s % gx, mb = s / gx;
    int m0 = mb * 128, n0 = nb * TN;
    int wr = (w >> 1) * 64, wc = (w & 1) * (TN / 2);

    f32x4 acc[4][NF] = {};

    int srow = (l >> 2);      // 0..15 within chunk
    int sch  = l & 3;         // 16B slot within 64B row

    for (int kk = 0; kk < K; kk += 32) {
        __syncthreads();
        // A planes: 128 rows = 4 waves x 2 chunks x 16
#pragma unroll
        for (int c = 0; c < 2; ++c) {
            int rbase = w * 32 + c * 16;
            int row = rbase + srow;
            int f = (row >> 1) & 3;
            size_t goff = (size_t)row * K + kk + (size_t)((sch ^ f)) * 8;
            gload_lds16(Ahp + (size_t)m0 * K + goff, &sA[0][rbase][0]);
            if (ALO) gload_lds16(Alp + (size_t)m0 * K + goff, &sA[AP - 1][rbase][0]);
        }
        // W planes: TN rows = 4 waves x (TN/64) chunks x 16
#pragma unroll
        for (int c = 0; c < TN / 64; ++c) {
            int rbase = w * (TN / 4) + c * 16;
            int row = rbase + srow;
            int f = (row >> 1) & 3;
            size_t goff = (size_t)row * K + kk + (size_t)((sch ^ f)) * 8;
            gload_lds16(Whp + (size_t)n0 * K + goff, &sW[0][rbase][0]);
            if (WLO) gload_lds16(Wlp + (size_t)n0 * K + goff, &sW[WP - 1][rbase][0]);
        }
        __syncthreads();

        bf16x8 a0[4], a1[4], b0[NF], b1[NF];
#pragma unroll
        for (int m = 0; m < 4; ++m) {
            int row = wr + m * 16 + lr;
            int sl = lg ^ ((row >> 1) & 3);
            a0[m] = *(const bf16x8*)&sA[0][row][sl * 8];
            if (ALO) a1[m] = *(const bf16x8*)&sA[AP - 1][row][sl * 8];
        }
#pragma unroll
        for (int n = 0; n < NF; ++n) {
            int row = wc + n * 16 + lr;
            int sl = lg ^ ((row >> 1) & 3);
            b0[n] = *(const bf16x8*)&sW[0][row][sl * 8];
            if (WLO) b1[n] = *(const bf16x8*)&sW[WP - 1][row][sl * 8];
        }
        // hh pass, then (if WLO) hl, then (if ALO) lh
#pragma unroll
        for (int m = 0; m < 4; ++m)
#pragma unroll
            for (int n = 0; n < NF; ++n)
                acc[m][n] = __builtin_amdgcn_mfma_f32_16x16x32_bf16(a0[m], b0[n], acc[m][n], 0, 0, 0);
        if (WLO) {
#pragma unroll
            for (int m = 0; m < 4; ++m)
#pragma unroll
                for (int n = 0; n < NF; ++n)
                    acc[m][n] = __builtin_amdgcn_mfma_f32_16x16x32_bf16(a0[m], b1[n], acc[m][n], 0, 0, 0);
        }
        if (ALO) {
#pragma unroll
            for (int m = 0; m < 4; ++m)
#pragma unroll
                for (int n = 0; n < NF; ++n)
                    acc[m][n] = __builtin_amdgcn_mfma_f32_16x16x32_bf16(a1[m], b0[n], acc[m][n], 0, 0, 0);
        }
    }

#pragma unroll
    for (int m = 0; m < 4; ++m) {
#pragma unroll
        for (int n = 0; n < NF; ++n) {
            int col = n0 + wc + n * 16 + lr;
            float bv = bias[col];
#pragma unroll
            for (int r = 0; r < 4; ++r) {
                int row = m0 + wr + m * 16 + lg * 4 + r;
                float v = acc[m][n][r] + bv;
                if (RELU)  v = (v >= 0.0f) ? v : 0.1f * v;
                if (RESID) v += resid[(size_t)row * N + col];
                if (OUTM == 0) {
                    outf[(size_t)row * N + col] = v;
                } else if (OUTM == 2) {
                    outh[(size_t)row * N + col] = (bf16_t)v;
                } else {
                    bf16_t h = (bf16_t)v;
                    outh[(size_t)row * N + col] = h;
                    outl[(size_t)row * N + col] = (bf16_t)(v - (float)h);
                }
            }
        }
    }
}

// ---------------------------------------------------------------------------
// Flash attention from fused QKV planes (row stride 3D; q/k/v at col 0/D/2D).
// Block = 256 thr (4 waves), 128 q-rows per block (32/wave).
// QK^T split-precision (3 MFMA/pair); PV pure bf16-hi. V staged hi-only.
// s_setprio(1) around MFMA clusters (m191: +4-7% on attn).
// ---------------------------------------------------------------------------
template<bool CAUSAL>
__global__ __launch_bounds__(256, 2) void attn_kernel(
    const bf16_t* __restrict__ qkvH, const bf16_t* __restrict__ qkvL,
    bf16_t* __restrict__ oh, bf16_t* __restrict__ ol)
{
    __shared__ bf16_t Vth[64][70];     // [e][kk] hi, pad 70 (~2-way banks)
    __shared__ bf16_t Ph[4][32][70];   // per-wave [qrow][kk] hi

    int tid = threadIdx.x;
    int qb = blockIdx.x, h = blockIdx.y, b = blockIdx.z;
    int l = tid & 63, w = tid >> 6;
    int lr = l & 15, lg = l >> 4;
    int qbase = qb * 128;
    const int QS = 3 * D;

    // Q frags: 32 rows per wave (2 x 16-row frags), hi/lo, both k-halves
    bf16x8 aqh[2][2], aql[2][2];
#pragma unroll
    for (int m = 0; m < 2; ++m) {
        size_t qoff = (size_t)(b * TT + qbase + w * 32 + m * 16 + lr) * QS + h * HS;
#pragma unroll
        for (int c = 0; c < 2; ++c) {
            aqh[m][c] = *(const bf16x8*)(qkvH + qoff + c * 32 + lg * 8);
            aql[m][c] = *(const bf16x8*)(qkvL + qoff + c * 32 + lg * 8);
        }
    }

    float mrow[2][4], lsum[2][4];
    f32x4 acc_o[2][4] = {};
#pragma unroll
    for (int m = 0; m < 2; ++m)
#pragma unroll
        for (int r = 0; r < 4; ++r) { mrow[m][r] = -1e30f; lsum[m][r] = 0.0f; }

    int ktmax = CAUSAL ? (2 * qb + 1) : (TT / 64 - 1);
    for (int kt = 0; kt <= ktmax; ++kt) {
        int kbase = kt * 64;
        __syncthreads();
        // stage V tile (hi only) transposed: Vth[e][kk]
#pragma unroll
        for (int rr = 0; rr < 2; ++rr) {
            int vrow = (tid >> 3) + rr * 32;
            int vcol = (tid & 7) * 8;
            size_t voff = (size_t)(b * TT + kbase + vrow) * QS + 2 * D + h * HS + vcol;
            bf16x8 vv = *(const bf16x8*)(qkvH + voff);
#pragma unroll
            for (int j = 0; j < 8; ++j) Vth[vcol + j][vrow] = vv[j];
        }
        __syncthreads();

        // S = Q K^T  (32 q-rows x 64 k-cols per wave), split 3-MFMA
        f32x4 accs[2][4];
        size_t koff = (size_t)(b * TT + kbase + lr) * QS + D + h * HS;
#pragma unroll
        for (int nt = 0; nt < 4; ++nt) {
            size_t ko = koff + (size_t)(nt * 16) * QS;
            bf16x8 bkh0 = *(const bf16x8*)(qkvH + ko + lg * 8);
            bf16x8 bkl0 = *(const bf16x8*)(qkvL + ko + lg * 8);
            bf16x8 bkh1 = *(const bf16x8*)(qkvH + ko + 32 + lg * 8);
            bf16x8 bkl1 = *(const bf16x8*)(qkvL + ko + 32 + lg * 8);
            __builtin_amdgcn_s_setprio(1);
#pragma unroll
            for (int m = 0; m < 2; ++m) {
                f32x4 s = {};
                s = __builtin_amdgcn_mfma_f32_16x16x32_bf16(aqh[m][0], bkh0, s, 0, 0, 0);
                s = __builtin_amdgcn_mfma_f32_16x16x32_bf16(aqh[m][0], bkl0, s, 0, 0, 0);
                s = __builtin_amdgcn_mfma_f32_16x16x32_bf16(aql[m][0], bkh0, s, 0, 0, 0);
                s = __builtin_amdgcn_mfma_f32_16x16x32_bf16(aqh[m][1], bkh1, s, 0, 0, 0);
                s = __builtin_amdgcn_mfma_f32_16x16x32_bf16(aqh[m][1], bkl1, s, 0, 0, 0);
                s = __builtin_amdgcn_mfma_f32_16x16x32_bf16(aql[m][1], bkh1, s, 0, 0, 0);
                accs[m][nt] = s * 8.0f;   // * sqrt(head_size), faithful to reference
            }
            __builtin_amdgcn_s_setprio(0);
        }

        if (CAUSAL && kt >= 2 * qb) {
#pragma unroll
            for (int m = 0; m < 2; ++m)
#pragma unroll
                for (int nt = 0; nt < 4; ++nt)
#pragma unroll
                    for (int r = 0; r < 4; ++r) {
                        int qrow = qbase + w * 32 + m * 16 + lg * 4 + r;
                        int kcol = kbase + nt * 16 + lr;
                        if (kcol > qrow) accs[m][nt][r] = -1e30f;
                    }
        }

        // online softmax (row-wise over the 16 lanes holding this row)
#pragma unroll
        for (int m = 0; m < 2; ++m) {
            float alpha[4];
#pragma unroll
            for (int r = 0; r < 4; ++r) {
                float mx = fmaxf(fmaxf(accs[m][0][r], accs[m][1][r]),
                                 fmaxf(accs[m][2][r], accs[m][3][r]));
#pragma unroll
                for (int msk = 1; msk < 16; msk <<= 1) mx = fmaxf(mx, __shfl_xor(mx, msk, 64));
                float mnew = fmaxf(mrow[m][r], mx);
                float sum = 0.0f;
#pragma unroll
                for (int nt = 0; nt < 4; ++nt) {
                    float p = __expf(accs[m][nt][r] - mnew);
                    accs[m][nt][r] = p;
                    sum += p;
                }
#pragma unroll
                for (int msk = 1; msk < 16; msk <<= 1) sum += __shfl_xor(sum, msk, 64);
                alpha[r] = __expf(mrow[m][r] - mnew);
                lsum[m][r] = lsum[m][r] * alpha[r] + sum;
                mrow[m][r] = mnew;
            }
#pragma unroll
            for (int et = 0; et < 4; ++et)
#pragma unroll
                for (int r = 0; r < 4; ++r) acc_o[m][et][r] *= alpha[r];

            // P -> LDS (bf16 hi only; wave-private, no barrier needed)
#pragma unroll
            for (int nt = 0; nt < 4; ++nt)
#pragma unroll
                for (int r = 0; r < 4; ++r)
                    Ph[w][m * 16 + lg * 4 + r][nt * 16 + lr] = (bf16_t)accs[m][nt][r];
        }

        // O += P @ V  (pure bf16)
#pragma unroll
        for (int m = 0; m < 2; ++m) {
            bf16x8 ap0 = *(const bf16x8*)&Ph[w][m * 16 + lr][lg * 8];
            bf16x8 ap1 = *(const bf16x8*)&Ph[w][m * 16 + lr][32 + lg * 8];
            __builtin_amdgcn_s_setprio(1);
#pragma unroll
            for (int et = 0; et < 4; ++et) {
                bf16x8 bv0 = *(const bf16x8*)&Vth[et * 16 + lr][lg * 8];
                bf16x8 bv1 = *(const bf16x8*)&Vth[et * 16 + lr][32 + lg * 8];
                acc_o[m][et] = __builtin_amdgcn_mfma_f32_16x16x32_bf16(ap0, bv0, acc_o[m][et], 0, 0, 0);
                acc_o[m][et] = __builtin_amdgcn_mfma_f32_16x16x32_bf16(ap1, bv1, acc_o[m][et], 0, 0, 0);
            }
            __builtin_amdgcn_s_setprio(0);
        }
    }

#pragma unroll
    for (int m = 0; m < 2; ++m) {
        size_t obase = (size_t)(b * TT + qbase + w * 32 + m * 16) * D + h * HS;
#pragma unroll
        for (int r = 0; r < 4; ++r) {
            float inv = 1.0f / lsum[m][r];
#pragma unroll
            for (int et = 0; et < 4; ++et) {
                float v = acc_o[m][et][r] * inv;
                bf16_t hh = (bf16_t)v;
                size_t idx = obase + (size_t)(lg * 4 + r) * D + et * 16 + lr;
                oh[idx] = hh;
                ol[idx] = (bf16_t)(v - (float)hh);
            }
        }
    }
}

// ---------------------------------------------------------------------------
extern "C" void kernel_launch(void* const* d_in, const int* in_sizes, int n_in,
                              void* d_out, int out_size, void* d_ws, size_t ws_size,
                              hipStream_t stream)
{
    const float* x     = (const float*)d_in[0];
    const float* Wq    = (const float*)d_in[1];
    const float* bq    = (const float*)d_in[2];
    const float* Wk    = (const float*)d_in[3];
    const float* bk    = (const float*)d_in[4];
    const float* Wv    = (const float*)d_in[5];
    const float* bv    = (const float*)d_in[6];
    const float* Wp    = (const float*)d_in[7];
    const float* bp    = (const float*)d_in[8];
    const float* gamma = (const float*)d_in[9];
    const float* W1    = (const float*)d_in[10];
    const float* b1    = (const float*)d_in[11];
    const float* W2    = (const float*)d_in[12];
    const float* b2    = (const float*)d_in[13];
    float* out = (float*)d_out;

    // workspace layout (96 MB):
    //  0..16  : nrm hi/lo (8 MB each); also ao hi/lo (aliased)
    // 16..64  : qkv hi (24) + qkv lo (24); h1 bf16-hi (32) aliases 16..48
    // 48..64  : W1 conv slot (16 MB, ffn phase; aliases qkv lo tail)
    // 64..80  : bias3072 (attn phases) / W2 conv slot (8 MB used, ffn phase)
    // 80..96  : persistent attn weights: wqkv hi 6, wqkv lo 6, wp hi 2, wp lo 2
    char* base = (char*)d_ws;
    bf16_t* nrmH  = (bf16_t*)(base);
    bf16_t* nrmL  = (bf16_t*)(base + (8u  << 20));
    bf16_t* qkvH  = (bf16_t*)(base + (16u << 20));
    bf16_t* qkvL  = (bf16_t*)(base + (40u << 20));
    bf16_t* h1H   = (bf16_t*)(base + (16u << 20));   // 32 MB, hi only
    bf16_t* w1sl  = (bf16_t*)(base + (48u << 20));   // 16 MB (hi+lo)
    float*  bias3 = (float*)(base + (64u << 20));
    bf16_t* w2sl  = (bf16_t*)(base + (64u << 20));   // 8 MB (hi only)
    bf16_t* wsl   = (bf16_t*)(base + (80u << 20));   // 16 MB persistent
    bf16_t* aoH = nrmH, *aoL = nrmL;
    float* abuf = out;   // 'a' lives in d_out, dead before final write
    float* bbuf = out;   // 'b' overwrites 'a' in d_out (a unused after rmsnorm)

    // persistent attn weights: wqkv hi [3072][1024], wqkv lo, wp hi, wp lo
    size_t DD = (size_t)D * D;
    bf16_t* wqkvH = wsl;
    bf16_t* wqkvL = wsl + 3 * DD;
    bf16_t* wpH   = wsl + 6 * DD;
    bf16_t* wpL   = wsl + 7 * DD;

    dim3 blk(256);
    dim3 gcvD(D / 64, D / 64);
    dim3 gcv1(D / 64, HF / 64);
    dim3 gcv2(HF / 64, D / 64);
    dim3 gQKV(3 * D / 128, MR / 128);   // 24 x 32 = 768 blocks, TN=128
    dim3 gP(D / 64, MR / 128);          // 16 x 32 = 512 blocks, TN=64
    dim3 gF(HF / 128, MR / 128);        // 32 x 32 = 1024 blocks, TN=128
    dim3 gA(TT / 128, NH, BB);          // 8 x 16 x 4 = 512 blocks

    // ---- a = x + attn(rmsnorm(x), causal=false)
    rmsnorm_kernel<true><<<MR, blk, 0, stream>>>(x, gamma, nrmH, nrmL);
    concat_bias_kernel<<<12, blk, 0, stream>>>(bq, bk, bv, bias3);
    convw_kernel<true><<<gcvD, blk, 0, stream>>>(Wq, wqkvH,          wqkvL,          D, D);
    convw_kernel<true><<<gcvD, blk, 0, stream>>>(Wk, wqkvH + DD,     wqkvL + DD,     D, D);
    convw_kernel<true><<<gcvD, blk, 0, stream>>>(Wv, wqkvH + 2 * DD, wqkvL + 2 * DD, D, D);
    convw_kernel<true><<<gcvD, blk, 0, stream>>>(Wp, wpH,            wpL,            D, D);
    gemm_kernel<128, true, true, 1, false, false><<<gQKV, blk, 0, stream>>>(nrmH, nrmL, wqkvH, wqkvL, bias3, nullptr, nullptr, qkvH, qkvL, 3 * D, D);
    attn_kernel<false><<<gA, blk, 0, stream>>>(qkvH, qkvL, aoH, aoL);
    gemm_kernel<64, true, true, 0, false, true><<<gP, blk, 0, stream>>>(aoH, aoL, wpH, wpL, bp, x, abuf, nullptr, nullptr, D, D);

    // ---- b = x + ffwd(rmsnorm(a))
    rmsnorm_kernel<false><<<MR, blk, 0, stream>>>(abuf, gamma, nrmH, nullptr);
    convw_kernel<true><<<gcv1, blk, 0, stream>>>(W1, w1sl, w1sl + (size_t)HF * D, D, HF);
    gemm_kernel<128, false, true, 2, true, false><<<gF, blk, 0, stream>>>(nrmH, nullptr, w1sl, w1sl + (size_t)HF * D, b1, nullptr, nullptr, h1H, nullptr, HF, D);
    convw_kernel<false><<<gcv2, blk, 0, stream>>>(W2, w2sl, nullptr, HF, D);
    gemm_kernel<64, false, false, 0, false, true><<<gP, blk, 0, stream>>>(h1H, nullptr, w2sl, nullptr, b2, x, bbuf, nullptr, nullptr, D, HF);

    // ---- c = b + attn(rmsnorm(b), causal=true)  (attn weights still resident)
    rmsnorm_kernel<true><<<MR, blk, 0, stream>>>(bbuf, gamma, nrmH, nrmL);
    concat_bias_kernel<<<12, blk, 0, stream>>>(bq, bk, bv, bias3);
    gemm_kernel<128, true, true, 1, false, false><<<gQKV, blk, 0, stream>>>(nrmH, nrmL, wqkvH, wqkvL, bias3, nullptr, nullptr, qkvH, qkvL, 3 * D, D);
    attn_kernel<true><<<gA, blk, 0, stream>>>(qkvH, qkvL, aoH, aoL);
    gemm_kernel<64, true, true, 0, false, true><<<gP, blk, 0, stream>>>(aoH, aoL, wpH, wpL, bp, bbuf, out, nullptr, nullptr, D, D);
}